// Round 19
// baseline (4191.174 us; speedup 1.0000x reference)
//
#include <hip/hip_runtime.h>
#include <hip/hip_fp16.h>

// ---------------- dimensions ----------------
constexpr int T_IN = 4096, W_IN = 128;
constexpr int H1 = 4092, W1 = 124, C1 = 16;
constexpr int H2 = 4088, W2 = 120, C2 = 32;
constexpr int H3 = 4084, W3 = 116, C3 = 64;
constexpr int HP = 4080, WPW = 58;      // pooled
constexpr int KF = 3712;                // 64*58 flattened features

typedef float f32x16 __attribute__((ext_vector_type(16)));
typedef _Float16 f16x16 __attribute__((ext_vector_type(16)));
typedef _Float16 half2_t __attribute__((ext_vector_type(2)));

// 25 fp32 input taps as NAMED scalars
#define LOAD25(SRC, W) \
    float p00=(SRC)[0],        p01=(SRC)[1],        p02=(SRC)[2],        p03=(SRC)[3],        p04=(SRC)[4]; \
    float p10=(SRC)[(W)],      p11=(SRC)[(W)+1],    p12=(SRC)[(W)+2],    p13=(SRC)[(W)+3],    p14=(SRC)[(W)+4]; \
    float p20=(SRC)[2*(W)],    p21=(SRC)[2*(W)+1],  p22=(SRC)[2*(W)+2],  p23=(SRC)[2*(W)+3],  p24=(SRC)[2*(W)+4]; \
    float p30=(SRC)[3*(W)],    p31=(SRC)[3*(W)+1],  p32=(SRC)[3*(W)+2],  p33=(SRC)[3*(W)+3],  p34=(SRC)[3*(W)+4]; \
    float p40=(SRC)[4*(W)],    p41=(SRC)[4*(W)+1],  p42=(SRC)[4*(W)+2],  p43=(SRC)[4*(W)+3],  p44=(SRC)[4*(W)+4];

#define TAPS25(T) \
    T(p00, 0)  T(p01, 1)  T(p02, 2)  T(p03, 3)  T(p04, 4) \
    T(p10, 5)  T(p11, 6)  T(p12, 7)  T(p13, 8)  T(p14, 9) \
    T(p20,10)  T(p21,11)  T(p22,12)  T(p23,13)  T(p24,14) \
    T(p30,15)  T(p31,16)  T(p32,17)  T(p33,18)  T(p34,19) \
    T(p40,20)  T(p41,21)  T(p42,22)  T(p43,23)  T(p44,24)

// 16 FMAs into 4 named float4 accumulators (fp32 path, conv1)
#define KSTEP16(PK, WPTR) do { \
    const float4* w4_ = (const float4*)(WPTR); \
    float4 wA_ = w4_[0], wB_ = w4_[1], wC_ = w4_[2], wD_ = w4_[3]; \
    a0.x = fmaf((PK), wA_.x, a0.x); a0.y = fmaf((PK), wA_.y, a0.y); \
    a0.z = fmaf((PK), wA_.z, a0.z); a0.w = fmaf((PK), wA_.w, a0.w); \
    a1.x = fmaf((PK), wB_.x, a1.x); a1.y = fmaf((PK), wB_.y, a1.y); \
    a1.z = fmaf((PK), wB_.z, a1.z); a1.w = fmaf((PK), wB_.w, a1.w); \
    a2.x = fmaf((PK), wC_.x, a2.x); a2.y = fmaf((PK), wC_.y, a2.y); \
    a2.z = fmaf((PK), wC_.z, a2.z); a2.w = fmaf((PK), wC_.w, a2.w); \
    a3.x = fmaf((PK), wD_.x, a3.x); a3.y = fmaf((PK), wD_.y, a3.y); \
    a3.z = fmaf((PK), wD_.z, a3.z); a3.w = fmaf((PK), wD_.w, a3.w); \
} while (0)

// 25 fp16 taps as NAMED scalars
#define LOAD25H(SRC, W) \
    _Float16 q00=(_Float16)(SRC)[0],      q01=(_Float16)(SRC)[1],      q02=(_Float16)(SRC)[2],      q03=(_Float16)(SRC)[3],      q04=(_Float16)(SRC)[4]; \
    _Float16 q10=(_Float16)(SRC)[(W)],    q11=(_Float16)(SRC)[(W)+1],  q12=(_Float16)(SRC)[(W)+2],  q13=(_Float16)(SRC)[(W)+3],  q14=(_Float16)(SRC)[(W)+4]; \
    _Float16 q20=(_Float16)(SRC)[2*(W)],  q21=(_Float16)(SRC)[2*(W)+1],q22=(_Float16)(SRC)[2*(W)+2],q23=(_Float16)(SRC)[2*(W)+3],q24=(_Float16)(SRC)[2*(W)+4]; \
    _Float16 q30=(_Float16)(SRC)[3*(W)],  q31=(_Float16)(SRC)[3*(W)+1],q32=(_Float16)(SRC)[3*(W)+2],q33=(_Float16)(SRC)[3*(W)+3],q34=(_Float16)(SRC)[3*(W)+4]; \
    _Float16 q40=(_Float16)(SRC)[4*(W)],  q41=(_Float16)(SRC)[4*(W)+1],q42=(_Float16)(SRC)[4*(W)+2],q43=(_Float16)(SRC)[4*(W)+3],q44=(_Float16)(SRC)[4*(W)+4];

// 13 tap pairs (row-major tap order, last padded with 0)
#define MKPAIRS() \
    half2_t P0, P1, P2, P3, P4, P5, P6, P7, P8, P9, P10, P11, P12; \
    P0[0]=q00; P0[1]=q01;  P1[0]=q02; P1[1]=q03;  P2[0]=q04; P2[1]=q10; \
    P3[0]=q11; P3[1]=q12;  P4[0]=q13; P4[1]=q14;  P5[0]=q20; P5[1]=q21; \
    P6[0]=q22; P6[1]=q23;  P7[0]=q24; P7[1]=q30;  P8[0]=q31; P8[1]=q32; \
    P9[0]=q33; P9[1]=q34;  P10[0]=q40; P10[1]=q41; P11[0]=q42; P11[1]=q43; \
    P12[0]=q44; P12[1]=(_Float16)0.f;

// 16 dot2 into 4 named float4 accumulators; WPTR = half2_t* (16 entries)
#define DSTEP16(PH, WPTR) do { \
    const half2_t* wv_ = (const half2_t*)(WPTR); \
    a0.x = __builtin_amdgcn_fdot2((PH), wv_[0],  a0.x, false); \
    a0.y = __builtin_amdgcn_fdot2((PH), wv_[1],  a0.y, false); \
    a0.z = __builtin_amdgcn_fdot2((PH), wv_[2],  a0.z, false); \
    a0.w = __builtin_amdgcn_fdot2((PH), wv_[3],  a0.w, false); \
    a1.x = __builtin_amdgcn_fdot2((PH), wv_[4],  a1.x, false); \
    a1.y = __builtin_amdgcn_fdot2((PH), wv_[5],  a1.y, false); \
    a1.z = __builtin_amdgcn_fdot2((PH), wv_[6],  a1.z, false); \
    a1.w = __builtin_amdgcn_fdot2((PH), wv_[7],  a1.w, false); \
    a2.x = __builtin_amdgcn_fdot2((PH), wv_[8],  a2.x, false); \
    a2.y = __builtin_amdgcn_fdot2((PH), wv_[9],  a2.y, false); \
    a2.z = __builtin_amdgcn_fdot2((PH), wv_[10], a2.z, false); \
    a2.w = __builtin_amdgcn_fdot2((PH), wv_[11], a2.w, false); \
    a3.x = __builtin_amdgcn_fdot2((PH), wv_[12], a3.x, false); \
    a3.y = __builtin_amdgcn_fdot2((PH), wv_[13], a3.y, false); \
    a3.z = __builtin_amdgcn_fdot2((PH), wv_[14], a3.z, false); \
    a3.w = __builtin_amdgcn_fdot2((PH), wv_[15], a3.w, false); \
} while (0)

#define PAIRS13(D, CI) \
    D(P0,  ((CI)*13+ 0)) D(P1,  ((CI)*13+ 1)) D(P2,  ((CI)*13+ 2)) \
    D(P3,  ((CI)*13+ 3)) D(P4,  ((CI)*13+ 4)) D(P5,  ((CI)*13+ 5)) \
    D(P6,  ((CI)*13+ 6)) D(P7,  ((CI)*13+ 7)) D(P8,  ((CI)*13+ 8)) \
    D(P9,  ((CI)*13+ 9)) D(P10, ((CI)*13+10)) D(P11, ((CI)*13+11)) \
    D(P12, ((CI)*13+12))

// ---------------- conv1: 1 -> 16, fp32 math, fp16 out ---------------------
__global__ __launch_bounds__(256, 2) void conv1_k(const float* __restrict__ x,
        const float* __restrict__ wp, const float* __restrict__ b,
        __half* __restrict__ out) {
    int pos = blockIdx.x * 256 + threadIdx.x;
    if (pos >= H1 * W1) return;
    int h = pos / W1, wi = pos - h * W1;
    const float* src = x + h * W_IN + wi;
    const float4* b4 = (const float4*)b;
    float4 a0 = b4[0], a1 = b4[1], a2 = b4[2], a3 = b4[3];
    LOAD25(src, W_IN);
#define T1(P, K) KSTEP16(P, wp + (K) * 16);
    TAPS25(T1)
#undef T1
#pragma unroll
    for (int i = 0; i < 4; i++) {
        float4 v = (i == 0) ? a0 : (i == 1) ? a1 : (i == 2) ? a2 : a3;
        out[(size_t)(i * 4 + 0) * (H1 * W1) + pos] = __float2half(v.x);
        out[(size_t)(i * 4 + 1) * (H1 * W1) + pos] = __float2half(v.y);
        out[(size_t)(i * 4 + 2) * (H1 * W1) + pos] = __float2half(v.z);
        out[(size_t)(i * 4 + 3) * (H1 * W1) + pos] = __float2half(v.w);
    }
}

// ---------------- conv2: 16 -> 32, fp16 dot2, co split (2 x 16) -----------
__global__ __launch_bounds__(256, 2) void conv2_k(const __half* __restrict__ in,
        const _Float16* __restrict__ wp2, const float* __restrict__ b,
        __half* __restrict__ out) {
    int pos = blockIdx.x * 256 + threadIdx.x;
    if (pos >= H2 * W2) return;
    int co0 = blockIdx.y * 16;
    int h = pos / W2, wi = pos - h * W2;
    const float4* b4 = (const float4*)(b + co0);
    float4 a0 = b4[0], a1 = b4[1], a2 = b4[2], a3 = b4[3];
#pragma unroll 1
    for (int ci = 0; ci < C1; ci++) {
        const __half* src = in + (size_t)ci * (H1 * W1) + h * W1 + wi;
        LOAD25H(src, W1);
        MKPAIRS();
#define D2(PH, QI) DSTEP16(PH, wp2 + ((size_t)(QI) * C2 + co0) * 2);
        PAIRS13(D2, ci)
#undef D2
    }
#pragma unroll
    for (int i = 0; i < 4; i++) {
        float4 v = (i == 0) ? a0 : (i == 1) ? a1 : (i == 2) ? a2 : a3;
        out[(size_t)(co0 + i * 4 + 0) * (H2 * W2) + pos] = __float2half(v.x);
        out[(size_t)(co0 + i * 4 + 1) * (H2 * W2) + pos] = __float2half(v.y);
        out[(size_t)(co0 + i * 4 + 2) * (H2 * W2) + pos] = __float2half(v.z);
        out[(size_t)(co0 + i * 4 + 3) * (H2 * W2) + pos] = __float2half(v.w);
    }
}

// ---------------- conv3: 32 -> 64, fp16 dot2, co split (4 x 16) -----------
__global__ __launch_bounds__(256, 2) void conv3_k(const __half* __restrict__ in,
        const _Float16* __restrict__ wp2, const float* __restrict__ b,
        __half* __restrict__ out) {
    int pos = blockIdx.x * 256 + threadIdx.x;
    if (pos >= H3 * W3) return;
    int co0 = blockIdx.y * 16;
    int h = pos / W3, wi = pos - h * W3;
    const float4* b4 = (const float4*)(b + co0);
    float4 a0 = b4[0], a1 = b4[1], a2 = b4[2], a3 = b4[3];
#pragma unroll 1
    for (int ci = 0; ci < C2; ci++) {
        const __half* src = in + (size_t)ci * (H2 * W2) + h * W2 + wi;
        LOAD25H(src, W2);
        MKPAIRS();
#define D3(PH, QI) DSTEP16(PH, wp2 + ((size_t)(QI) * C3 + co0) * 2);
        PAIRS13(D3, ci)
#undef D3
    }
#pragma unroll
    for (int i = 0; i < 4; i++) {
        float4 v = (i == 0) ? a0 : (i == 1) ? a1 : (i == 2) ? a2 : a3;
        out[(size_t)(co0 + i * 4 + 0) * (H3 * W3) + pos] = __float2half(v.x);
        out[(size_t)(co0 + i * 4 + 1) * (H3 * W3) + pos] = __float2half(v.y);
        out[(size_t)(co0 + i * 4 + 2) * (H3 * W3) + pos] = __float2half(v.z);
        out[(size_t)(co0 + i * 4 + 3) * (H3 * W3) + pos] = __float2half(v.w);
    }
}

// ---------------- maxpool 5x2 stride 1,2 ----------------
__global__ __launch_bounds__(256) void pool_k(const __half* __restrict__ in,
        float* __restrict__ out) {
    int idx = blockIdx.x * 256 + threadIdx.x;
    if (idx >= C3 * HP * WPW) return;
    int w = idx % WPW; int rest = idx / WPW; int h = rest % HP; int c = rest / HP;
    const __half* base = in + (size_t)c * (H3 * W3) + (size_t)h * W3 + 2 * w;
    float m = -1e30f;
#pragma unroll
    for (int i = 0; i < 5; i++)
#pragma unroll
        for (int j = 0; j < 2; j++)
            m = fmaxf(m, __half2float(base[(size_t)i * W3 + j]));
    out[idx] = m;   // layout == flat view (HP, 3712)
}

// ---------------- lin1: (4080 x 3712) @ Wt(3712 x 64), K-split + atomics ---
__global__ __launch_bounds__(256, 2) void lin1_k(const float* __restrict__ X,
        const float* __restrict__ Wt, float* __restrict__ L) {
    __shared__ alignas(16) float Xs[64][68];
    int tid = threadIdx.x;
    int j = tid & 63, mg = tid >> 6;
    int m0 = blockIdx.x * 64;
    int c0 = blockIdx.y * 15;
    int c1 = (c0 + 15 < 58) ? c0 + 15 : 58;
    float4 la0 = {0.f,0.f,0.f,0.f}, la1 = la0, la2 = la0, la3 = la0;
    for (int cc = c0; cc < c1; cc++) {
        int k0 = cc * 64;
        __syncthreads();
#pragma unroll
        for (int tix = 0; tix < 16; tix++) {
            int idx = tid + tix * 256;
            int mm = idx >> 6, kk = idx & 63;
            int m = m0 + mm;
            Xs[kk][mm] = (m < HP) ? X[(size_t)m * KF + k0 + kk] : 0.f;
        }
        __syncthreads();
#pragma unroll 4
        for (int k = 0; k < 64; k++) {
            float wv = Wt[(size_t)(k0 + k) * 64 + j];
            const float4* xr = (const float4*)&Xs[k][mg * 16];
            float4 x0 = xr[0], x1 = xr[1], x2 = xr[2], x3 = xr[3];
            la0.x = fmaf(x0.x, wv, la0.x); la0.y = fmaf(x0.y, wv, la0.y);
            la0.z = fmaf(x0.z, wv, la0.z); la0.w = fmaf(x0.w, wv, la0.w);
            la1.x = fmaf(x1.x, wv, la1.x); la1.y = fmaf(x1.y, wv, la1.y);
            la1.z = fmaf(x1.z, wv, la1.z); la1.w = fmaf(x1.w, wv, la1.w);
            la2.x = fmaf(x2.x, wv, la2.x); la2.y = fmaf(x2.y, wv, la2.y);
            la2.z = fmaf(x2.z, wv, la2.z); la2.w = fmaf(x2.w, wv, la2.w);
            la3.x = fmaf(x3.x, wv, la3.x); la3.y = fmaf(x3.y, wv, la3.y);
            la3.z = fmaf(x3.z, wv, la3.z); la3.w = fmaf(x3.w, wv, la3.w);
        }
    }
    int mb = m0 + mg * 16;
#define LATOM(C, OFF) { int m = mb + (OFF); if (m < HP) atomicAdd(&L[(size_t)m * 64 + j], (C)); }
    LATOM(la0.x, 0)  LATOM(la0.y, 1)  LATOM(la0.z, 2)  LATOM(la0.w, 3)
    LATOM(la1.x, 4)  LATOM(la1.y, 5)  LATOM(la1.z, 6)  LATOM(la1.w, 7)
    LATOM(la2.x, 8)  LATOM(la2.y, 9)  LATOM(la2.z, 10) LATOM(la2.w, 11)
    LATOM(la3.x, 12) LATOM(la3.y, 13) LATOM(la3.z, 14) LATOM(la3.w, 15)
#undef LATOM
}

// ---------------- gi = L @ wih^T + bc, 8 rows per block -------------------
__global__ __launch_bounds__(192) void gi_k(const float* __restrict__ L,
        const float* __restrict__ wiht, const float* __restrict__ bc,
        float* __restrict__ gi) {
    __shared__ alignas(16) float Ls[8][64];
    int m0 = blockIdx.x * 8, g = threadIdx.x;
    for (int idx = g; idx < 512; idx += 192) {
        int r = idx >> 6, k = idx & 63;
        Ls[r][k] = L[(size_t)(m0 + r) * 64 + k];
    }
    __syncthreads();
    float bcv = bc[g];
#pragma unroll 1
    for (int r = 0; r < 8; r++) {
        float acc = bcv;
#pragma unroll
        for (int k = 0; k < 64; k++) acc = fmaf(Ls[r][k], wiht[k * 192 + g], acc);
        gi[(size_t)(m0 + r) * 192 + g] = acc;
    }
}

// ---------------- GRU: 2 blocks x ONE wave, ZERO barriers, fp16 dot2 ------
// Lane l holds ALL THREE gate rows of unit l as 12 f16x16 (96 VGPRs —
// feasible only in fp16; the f16x16 residency mechanism is validated by
// round-17's VGPR=44 with 4 resident vectors). No inter-lane exchange:
// no Ax, no barriers. h broadcast via 4x32B LDS reads; same-wave DS
// ordering (validated round 11) makes the h RAW safe with a compiler fence.
__global__ __launch_bounds__(64, 1) void gru_k(const float* __restrict__ gi0,
        const float* __restrict__ gi1, const _Float16* __restrict__ whh_h,
        const float* __restrict__ bhh, float* __restrict__ e,
        float* __restrict__ t) {
    const float* gi = blockIdx.x ? gi1 : gi0;
    float* out = blockIdx.x ? t : e;
    const int l = threadIdx.x;           // hidden unit, 0..63
    const f16x16* wrp = (const f16x16*)(whh_h + (size_t)l * 64);
    const f16x16* wzp = (const f16x16*)(whh_h + (size_t)(64 + l) * 64);
    const f16x16* wnp = (const f16x16*)(whh_h + (size_t)(128 + l) * 64);
    f16x16 wr0 = wrp[0], wr1 = wrp[1], wr2 = wrp[2], wr3 = wrp[3];
    f16x16 wz0 = wzp[0], wz1 = wzp[1], wz2 = wzp[2], wz3 = wzp[3];
    f16x16 wn0 = wnp[0], wn1 = wnp[1], wn2 = wnp[2], wn3 = wnp[3];
    float bhr = bhh[l], bhz = bhh[64 + l], bhn = bhh[128 + l];
    __shared__ alignas(64) _Float16 hs[64];
    const f16x16* hsv = (const f16x16*)hs;
    float h = 0.f;
    hs[l] = (_Float16)0.f;
    asm volatile("" ::: "memory");       // init write ordered before loop reads
    float p0 = gi[l], p1 = gi[64 + l], p2 = gi[128 + l];
#define DOT8(W, H, ACC) _Pragma("unroll") \
    for (int i_ = 0; i_ < 8; i_++) { \
        half2_t wa_; wa_[0] = (W)[2*i_]; wa_[1] = (W)[2*i_+1]; \
        half2_t ha_; ha_[0] = (H)[2*i_]; ha_[1] = (H)[2*i_+1]; \
        ACC = __builtin_amdgcn_fdot2(wa_, ha_, ACC, false); \
    }
#pragma unroll 1
    for (int m = 0; m < HP; m++) {
        f16x16 hv0 = hsv[0], hv1 = hsv[1], hv2 = hsv[2], hv3 = hsv[3];
        float c0 = p0, c1 = p1, c2 = p2;
        if (m + 1 < HP) {                // prefetch next gi; never drained
            const float* gp = gi + (size_t)(m + 1) * 192;
            p0 = gp[l]; p1 = gp[64 + l]; p2 = gp[128 + l];
        }
        float ar0 = 0.f, ar1 = 0.f, ar2 = 0.f, ar3 = 0.f;
        float az0 = 0.f, az1 = 0.f, az2 = 0.f, az3 = 0.f;
        float an0 = 0.f, an1 = 0.f, an2 = 0.f, an3 = 0.f;
        DOT8(wr0, hv0, ar0) DOT8(wr1, hv1, ar1) DOT8(wr2, hv2, ar2) DOT8(wr3, hv3, ar3)
        DOT8(wz0, hv0, az0) DOT8(wz1, hv1, az1) DOT8(wz2, hv2, az2) DOT8(wz3, hv3, az3)
        DOT8(wn0, hv0, an0) DOT8(wn1, hv1, an1) DOT8(wn2, hv2, an2) DOT8(wn3, hv3, an3)
        float ar = (ar0 + ar1) + (ar2 + ar3) + bhr;
        float az = (az0 + az1) + (az2 + az3) + bhz;
        float an = (an0 + an1) + (an2 + an3) + bhn;
        float rg = 1.f / (1.f + __expf(-(c0 + ar)));
        float zg = 1.f / (1.f + __expf(-(c1 + az)));
        float pre = c2 + rg * an;
        float ex = __expf(2.f * pre);
        float nn = 1.f - 2.f / (ex + 1.f);   // tanh, overflow-safe
        h = (1.f - zg) * nn + zg * h;
        hs[l] = (_Float16)h;                 // same-wave DS order, no barrier
        asm volatile("" ::: "memory");       // next-iter reads stay after it
        out[(size_t)m * 64 + l] = h;         // store stays in flight
    }
#undef DOT8
}

// ---------------- alignment column stats (online softmax over m) ----------
__global__ __launch_bounds__(256) void astat_k(const float* __restrict__ e,
        const float* __restrict__ t, float* __restrict__ pM,
        float* __restrict__ pZ) {
    __shared__ alignas(16) float Ts[64][68];
    __shared__ float Ms[4][64], Zs[4][64];
    int tid = threadIdx.x;
    int nl = tid & 63, ms = tid >> 6;
    int n0 = blockIdx.x * 64;
#pragma unroll
    for (int i = 0; i < 16; i++) {
        int idx = tid + i * 256;
        int rr = idx >> 6, kk = idx & 63;
        int n = n0 + rr;
        Ts[rr][kk] = (n < HP) ? t[(size_t)n * 64 + kk] : 0.f;
    }
    __syncthreads();
    float M = -1e30f, Z = 0.f;
    int m0 = blockIdx.y * 510;
    const float4* Trow = (const float4*)&Ts[nl][0];
    for (int m = m0 + ms; m < m0 + 510; m += 4) {
        const float4* er = (const float4*)(e + (size_t)m * 64);
        float a0 = 0, a1 = 0, a2 = 0, a3 = 0;
#pragma unroll
        for (int i = 0; i < 16; i++) {
            float4 evv = er[i], tv = Trow[i];
            a0 = fmaf(evv.x, tv.x, a0); a1 = fmaf(evv.y, tv.y, a1);
            a2 = fmaf(evv.z, tv.z, a2); a3 = fmaf(evv.w, tv.w, a3);
        }
        float s = (a0 + a1) + (a2 + a3);
        float nM = fmaxf(M, s);
        Z = Z * __expf(M - nM) + __expf(s - nM);
        M = nM;
    }
    Ms[ms][nl] = M; Zs[ms][nl] = Z;
    __syncthreads();
    if (ms == 0) {
#pragma unroll
        for (int i = 1; i < 4; i++) {
            float m2 = Ms[i][nl], z2 = Zs[i][nl];
            float nM = fmaxf(M, m2);
            Z = Z * __expf(M - nM) + z2 * __expf(m2 - nM);
            M = nM;
        }
        int n = n0 + nl;
        if (n < HP) { pM[(size_t)blockIdx.y * HP + n] = M; pZ[(size_t)blockIdx.y * HP + n] = Z; }
    }
}

// ---------------- attention logits ----------------
__global__ __launch_bounds__(256) void attnlog_k(const float* __restrict__ e,
        const float* __restrict__ aw, const float* __restrict__ ab,
        float* __restrict__ alog) {
    int m = blockIdx.x * 256 + threadIdx.x;
    if (m >= HP) return;
    float acc = ab[0];
    const float4* er = (const float4*)(e + (size_t)m * 64);
    const float4* ar = (const float4*)aw;
#pragma unroll
    for (int i = 0; i < 16; i++) {
        float4 evv = er[i], av = ar[i];
        acc += evv.x * av.x + evv.y * av.y + evv.z * av.z + evv.w * av.w;
    }
    alog[m] = acc;
}

// ---------------- reduce partial stats + attn softmax stats ---------------
__global__ __launch_bounds__(256) void reduce_k(const float* __restrict__ pM,
        const float* __restrict__ pZ, float* __restrict__ Mn,
        float* __restrict__ Zn, const float* __restrict__ alog,
        float* __restrict__ scal) {
    int tid = threadIdx.x;
    if (blockIdx.x < 16) {
        int n = blockIdx.x * 256 + tid;
        if (n >= HP) return;
        float M = pM[n], Z = pZ[n];
#pragma unroll
        for (int y = 1; y < 8; y++) {
            float m2 = pM[(size_t)y * HP + n], z2 = pZ[(size_t)y * HP + n];
            float nM = fmaxf(M, m2);
            Z = Z * __expf(M - nM) + z2 * __expf(m2 - nM);
            M = nM;
        }
        Mn[n] = M; Zn[n] = Z;
    } else {
        __shared__ float red[256];
        float m = -1e30f;
        for (int i = tid; i < HP; i += 256) m = fmaxf(m, alog[i]);
        red[tid] = m; __syncthreads();
        for (int s = 128; s > 0; s >>= 1) {
            if (tid < s) red[tid] = fmaxf(red[tid], red[tid + s]);
            __syncthreads();
        }
        float Ma = red[0]; __syncthreads();
        float z = 0.f;
        for (int i = tid; i < HP; i += 256) z += __expf(alog[i] - Ma);
        red[tid] = z; __syncthreads();
        for (int s = 128; s > 0; s >>= 1) {
            if (tid < s) red[tid] += red[tid + s];
            __syncthreads();
        }
        if (tid == 0) { scal[0] = Ma; scal[1] = red[0]; }
    }
}

// ---------------- Wmat rows m<64 ----------------
__global__ __launch_bounds__(256) void wmat_k(const float* __restrict__ e,
        const float* __restrict__ t, const float* __restrict__ Mn,
        const float* __restrict__ Zn, float* __restrict__ Wm) {
    __shared__ alignas(16) float Es[64][68];
    int tid = threadIdx.x;
#pragma unroll
    for (int i = 0; i < 16; i++) {
        int idx = tid + i * 256;
        int rr = idx >> 6, kk = idx & 63;
        Es[rr][kk] = e[(size_t)rr * 64 + kk];
    }
    __syncthreads();
    int n = blockIdx.x * 256 + tid;
    if (n >= HP) return;
    float tn[64];
    const float4* tr = (const float4*)(t + (size_t)n * 64);
    float4* tn4 = (float4*)tn;
#pragma unroll
    for (int i = 0; i < 16; i++) tn4[i] = tr[i];
    float mM = Mn[n], iZ = 1.f / Zn[n];
#pragma unroll 1
    for (int m = 0; m < 64; m++) {
        const float4* Er = (const float4*)&Es[m][0];
        float a0 = 0, a1 = 0, a2 = 0, a3 = 0;
#pragma unroll
        for (int i = 0; i < 16; i++) {
            float4 evv = Er[i], tv = tn4[i];
            a0 = fmaf(evv.x, tv.x, a0); a1 = fmaf(evv.y, tv.y, a1);
            a2 = fmaf(evv.z, tv.z, a2); a3 = fmaf(evv.w, tv.w, a3);
        }
        float s = (a0 + a1) + (a2 + a3);
        Wm[(size_t)m * HP + n] = __expf(s - mM) * iZ;
    }
}

// ---------------- t_prim = Wm(64 x 4080) @ t(4080 x 64), K-split atomics ---
__global__ __launch_bounds__(256) void tprim_k(const float* __restrict__ Wm,
        const float* __restrict__ t, float* __restrict__ tp) {
    __shared__ float Ws[64][64];
    __shared__ float Ts[64][64];
    int tid = threadIdx.x;
    int n0 = blockIdx.x * 64;
#pragma unroll
    for (int i = 0; i < 16; i++) {
        int idx = tid + i * 256;
        int r = idx >> 6, c = idx & 63;
        Ws[r][c] = (n0 + c < HP) ? Wm[(size_t)r * HP + n0 + c] : 0.f;
        Ts[r][c] = (n0 + r < HP) ? t[(size_t)(n0 + r) * 64 + c] : 0.f;
    }
    __syncthreads();
    int d = tid & 63, mg = tid >> 6;
    float acc[16];
#pragma unroll
    for (int i = 0; i < 16; i++) acc[i] = 0.f;
    for (int k = 0; k < 64; k++) {
        float tv = Ts[k][d];
#pragma unroll
        for (int mm = 0; mm < 16; mm++) acc[mm] = fmaf(Ws[mg * 16 + mm][k], tv, acc[mm]);
    }
#pragma unroll
    for (int mm = 0; mm < 16; mm++)
        atomicAdd(&tp[(size_t)(mg * 16 + mm) * 64 + d], acc[mm]);
}

// ---------------- epilogue ----------------
__global__ __launch_bounds__(256) void final_k(const float* __restrict__ tp,
        const float* __restrict__ e, const float* __restrict__ alog,
        const float* __restrict__ scal, const float* __restrict__ l3w,
        const float* __restrict__ l3b, const float* __restrict__ cw,
        const float* __restrict__ cb, float* __restrict__ out) {
    __shared__ float r1[64], hid[128];
    int tid = threadIdx.x;
    float Ma = scal[0], iZa = 1.f / scal[1];
    if (tid < 64) {
        float acc = 0.f;
        for (int m = 0; m < 64; m++) {
            float a = __expf(alog[m] - Ma) * iZa;
            acc += fabsf(tp[m * 64 + tid] - e[m * 64 + tid]) * a;
        }
        r1[tid] = fmaxf(acc, 0.f);
    }
    __syncthreads();
    if (tid < 128) {
        float acc = l3b[tid];
        for (int d = 0; d < 64; d++) acc = fmaf(r1[d], l3w[tid * 64 + d], acc);
        hid[tid] = fmaxf(acc, 0.f);
    }
    __syncthreads();
    if (tid < 2) {
        float acc = cb[tid];
        for (int j = 0; j < 128; j++) acc = fmaf(hid[j], cw[tid * 128 + j], acc);
        out[tid] = acc;
    }
}

// ---------------- weight packing ----------------
__global__ __launch_bounds__(256) void transpose_l1w_k(const float* __restrict__ w,
        float* __restrict__ wt) {
    int idx = blockIdx.x * 256 + threadIdx.x;
    if (idx >= KF * 64) return;
    int k = idx >> 6, j = idx & 63;
    wt[idx] = w[(size_t)j * KF + k];
}
__global__ __launch_bounds__(256) void pack_w1_k(const float* __restrict__ w,
        float* __restrict__ wp) {
    int idx = blockIdx.x * 256 + threadIdx.x;
    if (idx >= 400) return;
    int k = idx >> 4, co = idx & 15;
    wp[idx] = w[co * 25 + k];
}
// conv2 dot2 pack: entry (ci,q,co) -> half2 (taps 2q, 2q+1; pad 0)
__global__ __launch_bounds__(256) void pack_w2p_k(const float* __restrict__ w,
        _Float16* __restrict__ wp2) {
    int idx = blockIdx.x * 256 + threadIdx.x;
    if (idx >= 16 * 13 * 32) return;
    int co = idx & 31; int rest = idx >> 5;
    int q = rest % 13, ci = rest / 13;
    int t0 = 2 * q, t1 = 2 * q + 1;
    float v0 = (t0 < 25) ? w[co * 400 + ci * 25 + t0] : 0.f;
    float v1 = (t1 < 25) ? w[co * 400 + ci * 25 + t1] : 0.f;
    wp2[(size_t)idx * 2 + 0] = (_Float16)v0;
    wp2[(size_t)idx * 2 + 1] = (_Float16)v1;
}
// conv3 dot2 pack: entry (ci,q,co), co<64
__global__ __launch_bounds__(256) void pack_w3p_k(const float* __restrict__ w,
        _Float16* __restrict__ wp2) {
    int idx = blockIdx.x * 256 + threadIdx.x;
    if (idx >= 32 * 13 * 64) return;
    int co = idx & 63; int rest = idx >> 6;
    int q = rest % 13, ci = rest / 13;
    int t0 = 2 * q, t1 = 2 * q + 1;
    float v0 = (t0 < 25) ? w[co * 800 + ci * 25 + t0] : 0.f;
    float v1 = (t1 < 25) ? w[co * 800 + ci * 25 + t1] : 0.f;
    wp2[(size_t)idx * 2 + 0] = (_Float16)v0;
    wp2[(size_t)idx * 2 + 1] = (_Float16)v1;
}
__global__ __launch_bounds__(256) void pack_wih_k(const float* __restrict__ wih,
        const float* __restrict__ bih, const float* __restrict__ l1b,
        const float* __restrict__ whh, float* __restrict__ wiht,
        float* __restrict__ bc, _Float16* __restrict__ whh_h) {
    int idx = blockIdx.x * 256 + threadIdx.x;
    if (idx < 12288) {
        int g = idx % 192, k = idx / 192;
        wiht[idx] = wih[g * 64 + k];
        whh_h[idx] = (_Float16)whh[idx];
    }
    if (idx < 192) {
        float acc = bih[idx];
#pragma unroll
        for (int k = 0; k < 64; k++) acc = fmaf(wih[idx * 64 + k], l1b[k], acc);
        bc[idx] = acc;
    }
}

// ---------------- host ----------------
extern "C" void kernel_launch(void* const* d_in, const int* in_sizes, int n_in,
                              void* d_out, int out_size, void* d_ws, size_t ws_size,
                              hipStream_t stream) {
    const float* ev    = (const float*)d_in[0];
    const float* tmpl  = (const float*)d_in[1];
    const float* w1    = (const float*)d_in[2];
    const float* b1    = (const float*)d_in[3];
    const float* w2    = (const float*)d_in[4];
    const float* b2    = (const float*)d_in[5];
    const float* w3    = (const float*)d_in[6];
    const float* b3    = (const float*)d_in[7];
    const float* l1w   = (const float*)d_in[8];
    const float* l1b   = (const float*)d_in[9];
    const float* wih   = (const float*)d_in[10];
    const float* whh   = (const float*)d_in[11];
    const float* bih   = (const float*)d_in[12];
    const float* bhh   = (const float*)d_in[13];
    const float* aw    = (const float*)d_in[14];
    const float* ab    = (const float*)d_in[15];
    const float* l3w   = (const float*)d_in[16];
    const float* l3b   = (const float*)d_in[17];
    const float* cw    = (const float*)d_in[18];
    const float* cb    = (const float*)d_in[19];
    float* out = (float*)d_out;
    (void)in_sizes; (void)n_in; (void)out_size;

    char* ws = (char*)d_ws;
    size_t off = 0;
    auto alloc = [&](size_t bytes) -> char* {
        char* p = ws + off;
        off += (bytes + 255) & ~(size_t)255;
        return p;
    };
    size_t szA = (size_t)C3 * H3 * W3 * 2;                 // fp16 conv3 out (> conv1 out fp16)
    char*  A    = alloc(szA);
    float* B    = (float*)alloc((size_t)HP * KF * 4);      // conv2 fp16 out / pooled fp32
    float* Wt   = (float*)alloc((size_t)KF * 64 * 4);
    float* w1p  = (float*)alloc(400 * 4);
    _Float16* w2p2 = (_Float16*)alloc(16 * 13 * 32 * 2 * 2);
    _Float16* w3p2 = (_Float16*)alloc(32 * 13 * 64 * 2 * 2);
    float* wiht = (float*)alloc(12288 * 4);
    _Float16* whhh = (_Float16*)alloc(12288 * 2);
    float* bc   = (float*)alloc(256 * 4);
    float* L    = (float*)alloc((size_t)HP * 64 * 4);
    float* gi0  = (float*)alloc((size_t)HP * 192 * 4);
    float* gi1  = (float*)alloc((size_t)HP * 192 * 4);
    float* ebuf = (float*)alloc((size_t)HP * 64 * 4);
    float* tbuf = (float*)alloc((size_t)HP * 64 * 4);
    float* pM   = (float*)alloc((size_t)8 * HP * 4);
    float* pZ   = (float*)alloc((size_t)8 * HP * 4);
    float* Mn   = (float*)alloc(HP * 4);
    float* Zn   = (float*)alloc(HP * 4);
    float* Wm   = (float*)alloc((size_t)64 * HP * 4);
    float* alog = (float*)alloc(HP * 4);
    float* tpm  = (float*)alloc(64 * 64 * 4);
    float* scal = (float*)alloc(256);
    if (off > ws_size) return;   // workspace too small: bail loudly (validation fails)

    transpose_l1w_k<<<dim3((KF * 64 + 255) / 256), dim3(256), 0, stream>>>(l1w, Wt);
    pack_w1_k<<<dim3(2), dim3(256), 0, stream>>>(w1, w1p);
    pack_w2p_k<<<dim3((16 * 13 * 32 + 255) / 256), dim3(256), 0, stream>>>(w2, w2p2);
    pack_w3p_k<<<dim3((32 * 13 * 64 + 255) / 256), dim3(256), 0, stream>>>(w3, w3p2);
    pack_wih_k<<<dim3(48), dim3(256), 0, stream>>>(wih, bih, l1b, whh, wiht, bc, whhh);

    for (int bsel = 0; bsel < 2; bsel++) {
        const float* xin = bsel ? tmpl : ev;
        float* gib = bsel ? gi1 : gi0;
        conv1_k<<<dim3((H1 * W1 + 255) / 256), dim3(256), 0, stream>>>(xin, w1p, b1, (__half*)A);
        conv2_k<<<dim3((H2 * W2 + 255) / 256, 2), dim3(256), 0, stream>>>((const __half*)A, w2p2, b2, (__half*)B);
        conv3_k<<<dim3((H3 * W3 + 255) / 256, 4), dim3(256), 0, stream>>>((const __half*)B, w3p2, b3, (__half*)A);
        pool_k<<<dim3((C3 * HP * WPW + 255) / 256), dim3(256), 0, stream>>>((const __half*)A, B);
        hipMemsetAsync(L, 0, (size_t)HP * 64 * 4, stream);
        lin1_k<<<dim3(64, 4), dim3(256), 0, stream>>>(B, Wt, L);
        gi_k<<<dim3(HP / 8), dim3(192), 0, stream>>>(L, wiht, bc, gib);
    }
    gru_k<<<dim3(2), dim3(64), 0, stream>>>(gi0, gi1, whhh, bhh, ebuf, tbuf);
    astat_k<<<dim3(64, 8), dim3(256), 0, stream>>>(ebuf, tbuf, pM, pZ);
    attnlog_k<<<dim3(16), dim3(256), 0, stream>>>(ebuf, aw, ab, alog);
    reduce_k<<<dim3(17), dim3(256), 0, stream>>>(pM, pZ, Mn, Zn, alog, scal);
    wmat_k<<<dim3(16), dim3(256), 0, stream>>>(ebuf, tbuf, Mn, Zn, Wm);
    hipMemsetAsync(tpm, 0, 64 * 64 * 4, stream);
    tprim_k<<<dim3(64), dim3(256), 0, stream>>>(Wm, tbuf, tpm);
    final_k<<<dim3(1), dim3(256), 0, stream>>>(tpm, ebuf, alog, scal, l3w, l3b, cw, cb, out);
}

// Round 20
// 3674.943 us; speedup vs baseline: 1.1405x; 1.1405x over previous
//
#include <hip/hip_runtime.h>
#include <hip/hip_fp16.h>

// ---------------- dimensions ----------------
constexpr int T_IN = 4096, W_IN = 128;
constexpr int H1 = 4092, W1 = 124, C1 = 16;
constexpr int H2 = 4088, W2 = 120, C2 = 32;
constexpr int H3 = 4084, W3 = 116, C3 = 64;
constexpr int HP = 4080, WPW = 58;      // pooled
constexpr int KF = 3712;                // 64*58 flattened features

typedef float f32x16 __attribute__((ext_vector_type(16)));
typedef _Float16 f16x16 __attribute__((ext_vector_type(16)));
typedef _Float16 half2_t __attribute__((ext_vector_type(2)));

// 25 fp32 input taps as NAMED scalars
#define LOAD25(SRC, W) \
    float p00=(SRC)[0],        p01=(SRC)[1],        p02=(SRC)[2],        p03=(SRC)[3],        p04=(SRC)[4]; \
    float p10=(SRC)[(W)],      p11=(SRC)[(W)+1],    p12=(SRC)[(W)+2],    p13=(SRC)[(W)+3],    p14=(SRC)[(W)+4]; \
    float p20=(SRC)[2*(W)],    p21=(SRC)[2*(W)+1],  p22=(SRC)[2*(W)+2],  p23=(SRC)[2*(W)+3],  p24=(SRC)[2*(W)+4]; \
    float p30=(SRC)[3*(W)],    p31=(SRC)[3*(W)+1],  p32=(SRC)[3*(W)+2],  p33=(SRC)[3*(W)+3],  p34=(SRC)[3*(W)+4]; \
    float p40=(SRC)[4*(W)],    p41=(SRC)[4*(W)+1],  p42=(SRC)[4*(W)+2],  p43=(SRC)[4*(W)+3],  p44=(SRC)[4*(W)+4];

#define TAPS25(T) \
    T(p00, 0)  T(p01, 1)  T(p02, 2)  T(p03, 3)  T(p04, 4) \
    T(p10, 5)  T(p11, 6)  T(p12, 7)  T(p13, 8)  T(p14, 9) \
    T(p20,10)  T(p21,11)  T(p22,12)  T(p23,13)  T(p24,14) \
    T(p30,15)  T(p31,16)  T(p32,17)  T(p33,18)  T(p34,19) \
    T(p40,20)  T(p41,21)  T(p42,22)  T(p43,23)  T(p44,24)

// 16 FMAs into 4 named float4 accumulators (fp32 path, conv1)
#define KSTEP16(PK, WPTR) do { \
    const float4* w4_ = (const float4*)(WPTR); \
    float4 wA_ = w4_[0], wB_ = w4_[1], wC_ = w4_[2], wD_ = w4_[3]; \
    a0.x = fmaf((PK), wA_.x, a0.x); a0.y = fmaf((PK), wA_.y, a0.y); \
    a0.z = fmaf((PK), wA_.z, a0.z); a0.w = fmaf((PK), wA_.w, a0.w); \
    a1.x = fmaf((PK), wB_.x, a1.x); a1.y = fmaf((PK), wB_.y, a1.y); \
    a1.z = fmaf((PK), wB_.z, a1.z); a1.w = fmaf((PK), wB_.w, a1.w); \
    a2.x = fmaf((PK), wC_.x, a2.x); a2.y = fmaf((PK), wC_.y, a2.y); \
    a2.z = fmaf((PK), wC_.z, a2.z); a2.w = fmaf((PK), wC_.w, a2.w); \
    a3.x = fmaf((PK), wD_.x, a3.x); a3.y = fmaf((PK), wD_.y, a3.y); \
    a3.z = fmaf((PK), wD_.z, a3.z); a3.w = fmaf((PK), wD_.w, a3.w); \
} while (0)

// 25 fp16 taps as NAMED scalars
#define LOAD25H(SRC, W) \
    _Float16 q00=(_Float16)(SRC)[0],      q01=(_Float16)(SRC)[1],      q02=(_Float16)(SRC)[2],      q03=(_Float16)(SRC)[3],      q04=(_Float16)(SRC)[4]; \
    _Float16 q10=(_Float16)(SRC)[(W)],    q11=(_Float16)(SRC)[(W)+1],  q12=(_Float16)(SRC)[(W)+2],  q13=(_Float16)(SRC)[(W)+3],  q14=(_Float16)(SRC)[(W)+4]; \
    _Float16 q20=(_Float16)(SRC)[2*(W)],  q21=(_Float16)(SRC)[2*(W)+1],q22=(_Float16)(SRC)[2*(W)+2],q23=(_Float16)(SRC)[2*(W)+3],q24=(_Float16)(SRC)[2*(W)+4]; \
    _Float16 q30=(_Float16)(SRC)[3*(W)],  q31=(_Float16)(SRC)[3*(W)+1],q32=(_Float16)(SRC)[3*(W)+2],q33=(_Float16)(SRC)[3*(W)+3],q34=(_Float16)(SRC)[3*(W)+4]; \
    _Float16 q40=(_Float16)(SRC)[4*(W)],  q41=(_Float16)(SRC)[4*(W)+1],q42=(_Float16)(SRC)[4*(W)+2],q43=(_Float16)(SRC)[4*(W)+3],q44=(_Float16)(SRC)[4*(W)+4];

// 13 tap pairs (row-major tap order, last padded with 0)
#define MKPAIRS() \
    half2_t P0, P1, P2, P3, P4, P5, P6, P7, P8, P9, P10, P11, P12; \
    P0[0]=q00; P0[1]=q01;  P1[0]=q02; P1[1]=q03;  P2[0]=q04; P2[1]=q10; \
    P3[0]=q11; P3[1]=q12;  P4[0]=q13; P4[1]=q14;  P5[0]=q20; P5[1]=q21; \
    P6[0]=q22; P6[1]=q23;  P7[0]=q24; P7[1]=q30;  P8[0]=q31; P8[1]=q32; \
    P9[0]=q33; P9[1]=q34;  P10[0]=q40; P10[1]=q41; P11[0]=q42; P11[1]=q43; \
    P12[0]=q44; P12[1]=(_Float16)0.f;

// 16 dot2 into 4 named float4 accumulators; WPTR = half2_t* (16 entries)
#define DSTEP16(PH, WPTR) do { \
    const half2_t* wv_ = (const half2_t*)(WPTR); \
    a0.x = __builtin_amdgcn_fdot2((PH), wv_[0],  a0.x, false); \
    a0.y = __builtin_amdgcn_fdot2((PH), wv_[1],  a0.y, false); \
    a0.z = __builtin_amdgcn_fdot2((PH), wv_[2],  a0.z, false); \
    a0.w = __builtin_amdgcn_fdot2((PH), wv_[3],  a0.w, false); \
    a1.x = __builtin_amdgcn_fdot2((PH), wv_[4],  a1.x, false); \
    a1.y = __builtin_amdgcn_fdot2((PH), wv_[5],  a1.y, false); \
    a1.z = __builtin_amdgcn_fdot2((PH), wv_[6],  a1.z, false); \
    a1.w = __builtin_amdgcn_fdot2((PH), wv_[7],  a1.w, false); \
    a2.x = __builtin_amdgcn_fdot2((PH), wv_[8],  a2.x, false); \
    a2.y = __builtin_amdgcn_fdot2((PH), wv_[9],  a2.y, false); \
    a2.z = __builtin_amdgcn_fdot2((PH), wv_[10], a2.z, false); \
    a2.w = __builtin_amdgcn_fdot2((PH), wv_[11], a2.w, false); \
    a3.x = __builtin_amdgcn_fdot2((PH), wv_[12], a3.x, false); \
    a3.y = __builtin_amdgcn_fdot2((PH), wv_[13], a3.y, false); \
    a3.z = __builtin_amdgcn_fdot2((PH), wv_[14], a3.z, false); \
    a3.w = __builtin_amdgcn_fdot2((PH), wv_[15], a3.w, false); \
} while (0)

#define PAIRS13(D, CI) \
    D(P0,  ((CI)*13+ 0)) D(P1,  ((CI)*13+ 1)) D(P2,  ((CI)*13+ 2)) \
    D(P3,  ((CI)*13+ 3)) D(P4,  ((CI)*13+ 4)) D(P5,  ((CI)*13+ 5)) \
    D(P6,  ((CI)*13+ 6)) D(P7,  ((CI)*13+ 7)) D(P8,  ((CI)*13+ 8)) \
    D(P9,  ((CI)*13+ 9)) D(P10, ((CI)*13+10)) D(P11, ((CI)*13+11)) \
    D(P12, ((CI)*13+12))

// ---------------- conv1: 1 -> 16, fp32 math, fp16 out ---------------------
__global__ __launch_bounds__(256, 2) void conv1_k(const float* __restrict__ x,
        const float* __restrict__ wp, const float* __restrict__ b,
        __half* __restrict__ out) {
    int pos = blockIdx.x * 256 + threadIdx.x;
    if (pos >= H1 * W1) return;
    int h = pos / W1, wi = pos - h * W1;
    const float* src = x + h * W_IN + wi;
    const float4* b4 = (const float4*)b;
    float4 a0 = b4[0], a1 = b4[1], a2 = b4[2], a3 = b4[3];
    LOAD25(src, W_IN);
#define T1(P, K) KSTEP16(P, wp + (K) * 16);
    TAPS25(T1)
#undef T1
#pragma unroll
    for (int i = 0; i < 4; i++) {
        float4 v = (i == 0) ? a0 : (i == 1) ? a1 : (i == 2) ? a2 : a3;
        out[(size_t)(i * 4 + 0) * (H1 * W1) + pos] = __float2half(v.x);
        out[(size_t)(i * 4 + 1) * (H1 * W1) + pos] = __float2half(v.y);
        out[(size_t)(i * 4 + 2) * (H1 * W1) + pos] = __float2half(v.z);
        out[(size_t)(i * 4 + 3) * (H1 * W1) + pos] = __float2half(v.w);
    }
}

// ---------------- conv2: 16 -> 32, fp16 dot2; co-group = blockIdx.x -------
// (co-groups of one spatial tile dispatch back-to-back -> input L2/L1 hit)
__global__ __launch_bounds__(256, 2) void conv2_k(const __half* __restrict__ in,
        const _Float16* __restrict__ wp2, const float* __restrict__ b,
        __half* __restrict__ out) {
    int pos = blockIdx.y * 256 + threadIdx.x;
    if (pos >= H2 * W2) return;
    int co0 = blockIdx.x * 16;
    int h = pos / W2, wi = pos - h * W2;
    const float4* b4 = (const float4*)(b + co0);
    float4 a0 = b4[0], a1 = b4[1], a2 = b4[2], a3 = b4[3];
#pragma unroll 1
    for (int ci = 0; ci < C1; ci++) {
        const __half* src = in + (size_t)ci * (H1 * W1) + h * W1 + wi;
        LOAD25H(src, W1);
        MKPAIRS();
#define D2(PH, QI) DSTEP16(PH, wp2 + ((size_t)(QI) * C2 + co0) * 2);
        PAIRS13(D2, ci)
#undef D2
    }
#pragma unroll
    for (int i = 0; i < 4; i++) {
        float4 v = (i == 0) ? a0 : (i == 1) ? a1 : (i == 2) ? a2 : a3;
        out[(size_t)(co0 + i * 4 + 0) * (H2 * W2) + pos] = __float2half(v.x);
        out[(size_t)(co0 + i * 4 + 1) * (H2 * W2) + pos] = __float2half(v.y);
        out[(size_t)(co0 + i * 4 + 2) * (H2 * W2) + pos] = __float2half(v.z);
        out[(size_t)(co0 + i * 4 + 3) * (H2 * W2) + pos] = __float2half(v.w);
    }
}

// ---------------- conv3: 32 -> 64, fp16 dot2; co-group = blockIdx.x -------
__global__ __launch_bounds__(256, 2) void conv3_k(const __half* __restrict__ in,
        const _Float16* __restrict__ wp2, const float* __restrict__ b,
        __half* __restrict__ out) {
    int pos = blockIdx.y * 256 + threadIdx.x;
    if (pos >= H3 * W3) return;
    int co0 = blockIdx.x * 16;
    int h = pos / W3, wi = pos - h * W3;
    const float4* b4 = (const float4*)(b + co0);
    float4 a0 = b4[0], a1 = b4[1], a2 = b4[2], a3 = b4[3];
#pragma unroll 1
    for (int ci = 0; ci < C2; ci++) {
        const __half* src = in + (size_t)ci * (H2 * W2) + h * W2 + wi;
        LOAD25H(src, W2);
        MKPAIRS();
#define D3(PH, QI) DSTEP16(PH, wp2 + ((size_t)(QI) * C3 + co0) * 2);
        PAIRS13(D3, ci)
#undef D3
    }
#pragma unroll
    for (int i = 0; i < 4; i++) {
        float4 v = (i == 0) ? a0 : (i == 1) ? a1 : (i == 2) ? a2 : a3;
        out[(size_t)(co0 + i * 4 + 0) * (H3 * W3) + pos] = __float2half(v.x);
        out[(size_t)(co0 + i * 4 + 1) * (H3 * W3) + pos] = __float2half(v.y);
        out[(size_t)(co0 + i * 4 + 2) * (H3 * W3) + pos] = __float2half(v.z);
        out[(size_t)(co0 + i * 4 + 3) * (H3 * W3) + pos] = __float2half(v.w);
    }
}

// ---------------- maxpool 5x2 stride 1,2 ----------------
__global__ __launch_bounds__(256) void pool_k(const __half* __restrict__ in,
        float* __restrict__ out) {
    int idx = blockIdx.x * 256 + threadIdx.x;
    if (idx >= C3 * HP * WPW) return;
    int w = idx % WPW; int rest = idx / WPW; int h = rest % HP; int c = rest / HP;
    const __half* base = in + (size_t)c * (H3 * W3) + (size_t)h * W3 + 2 * w;
    float m = -1e30f;
#pragma unroll
    for (int i = 0; i < 5; i++)
#pragma unroll
        for (int j = 0; j < 2; j++)
            m = fmaxf(m, __half2float(base[(size_t)i * W3 + j]));
    out[idx] = m;   // layout == flat view (HP, 3712)
}

// ---------------- lin1: (4080 x 3712) @ Wt(3712 x 64), K-split + atomics ---
__global__ __launch_bounds__(256, 2) void lin1_k(const float* __restrict__ X,
        const float* __restrict__ Wt, float* __restrict__ L) {
    __shared__ alignas(16) float Xs[64][68];
    int tid = threadIdx.x;
    int j = tid & 63, mg = tid >> 6;
    int m0 = blockIdx.x * 64;
    int c0 = blockIdx.y * 15;
    int c1 = (c0 + 15 < 58) ? c0 + 15 : 58;
    float4 la0 = {0.f,0.f,0.f,0.f}, la1 = la0, la2 = la0, la3 = la0;
    for (int cc = c0; cc < c1; cc++) {
        int k0 = cc * 64;
        __syncthreads();
#pragma unroll
        for (int tix = 0; tix < 16; tix++) {
            int idx = tid + tix * 256;
            int mm = idx >> 6, kk = idx & 63;
            int m = m0 + mm;
            Xs[kk][mm] = (m < HP) ? X[(size_t)m * KF + k0 + kk] : 0.f;
        }
        __syncthreads();
#pragma unroll 4
        for (int k = 0; k < 64; k++) {
            float wv = Wt[(size_t)(k0 + k) * 64 + j];
            const float4* xr = (const float4*)&Xs[k][mg * 16];
            float4 x0 = xr[0], x1 = xr[1], x2 = xr[2], x3 = xr[3];
            la0.x = fmaf(x0.x, wv, la0.x); la0.y = fmaf(x0.y, wv, la0.y);
            la0.z = fmaf(x0.z, wv, la0.z); la0.w = fmaf(x0.w, wv, la0.w);
            la1.x = fmaf(x1.x, wv, la1.x); la1.y = fmaf(x1.y, wv, la1.y);
            la1.z = fmaf(x1.z, wv, la1.z); la1.w = fmaf(x1.w, wv, la1.w);
            la2.x = fmaf(x2.x, wv, la2.x); la2.y = fmaf(x2.y, wv, la2.y);
            la2.z = fmaf(x2.z, wv, la2.z); la2.w = fmaf(x2.w, wv, la2.w);
            la3.x = fmaf(x3.x, wv, la3.x); la3.y = fmaf(x3.y, wv, la3.y);
            la3.z = fmaf(x3.z, wv, la3.z); la3.w = fmaf(x3.w, wv, la3.w);
        }
    }
    int mb = m0 + mg * 16;
#define LATOM(C, OFF) { int m = mb + (OFF); if (m < HP) atomicAdd(&L[(size_t)m * 64 + j], (C)); }
    LATOM(la0.x, 0)  LATOM(la0.y, 1)  LATOM(la0.z, 2)  LATOM(la0.w, 3)
    LATOM(la1.x, 4)  LATOM(la1.y, 5)  LATOM(la1.z, 6)  LATOM(la1.w, 7)
    LATOM(la2.x, 8)  LATOM(la2.y, 9)  LATOM(la2.z, 10) LATOM(la2.w, 11)
    LATOM(la3.x, 12) LATOM(la3.y, 13) LATOM(la3.z, 14) LATOM(la3.w, 15)
#undef LATOM
}

// ---------------- gi = L @ wih^T + bc, 8 rows per block -------------------
__global__ __launch_bounds__(192) void gi_k(const float* __restrict__ L,
        const float* __restrict__ wiht, const float* __restrict__ bc,
        float* __restrict__ gi) {
    __shared__ alignas(16) float Ls[8][64];
    int m0 = blockIdx.x * 8, g = threadIdx.x;
    for (int idx = g; idx < 512; idx += 192) {
        int r = idx >> 6, k = idx & 63;
        Ls[r][k] = L[(size_t)(m0 + r) * 64 + k];
    }
    __syncthreads();
    float bcv = bc[g];
#pragma unroll 1
    for (int r = 0; r < 8; r++) {
        float acc = bcv;
#pragma unroll
        for (int k = 0; k < 64; k++) acc = fmaf(Ls[r][k], wiht[k * 192 + g], acc);
        gi[(size_t)(m0 + r) * 192 + g] = acc;
    }
}

// ---------------- GRU: 3 waves, 2 lgkm barriers, fp16 dot2 (round-18 best)-
__global__ __launch_bounds__(192, 1) void gru_k(const float* __restrict__ gi0,
        const float* __restrict__ gi1, const _Float16* __restrict__ whh_h,
        const float* __restrict__ bhh, float* __restrict__ e,
        float* __restrict__ t) {
    const float* gi = blockIdx.x ? gi1 : gi0;
    float* out = blockIdx.x ? t : e;
    const int g = threadIdx.x;           // gate row, 0..191
    const f16x16* wp = (const f16x16*)(whh_h + (size_t)g * 64);
    f16x16 w0 = wp[0], w1 = wp[1], w2 = wp[2], w3 = wp[3];
    float bh = bhh[g];
    __shared__ alignas(64) _Float16 hs[64];
    __shared__ float Ax[192];
    const f16x16* hsv = (const f16x16*)hs;
    float h = 0.f;
    if (g < 64) hs[g] = (_Float16)0.f;
    __syncthreads();
    float p0 = 0.f, p1 = 0.f, p2 = 0.f;  // gi prefetch (lanes<64 only)
    if (g < 64) { p0 = gi[g]; p1 = gi[64 + g]; p2 = gi[128 + g]; }
#define LGKM_BARRIER() do { \
    asm volatile("s_waitcnt lgkmcnt(0)" ::: "memory"); \
    __builtin_amdgcn_s_barrier(); \
    asm volatile("" ::: "memory"); \
} while (0)
#define DOT8(W, H, ACC) _Pragma("unroll") \
    for (int i_ = 0; i_ < 8; i_++) { \
        half2_t wa_; wa_[0] = (W)[2*i_]; wa_[1] = (W)[2*i_+1]; \
        half2_t ha_; ha_[0] = (H)[2*i_]; ha_[1] = (H)[2*i_+1]; \
        ACC = __builtin_amdgcn_fdot2(wa_, ha_, ACC, false); \
    }
#pragma unroll 1
    for (int m = 0; m < HP; m++) {
        f16x16 hv0 = hsv[0], hv1 = hsv[1], hv2 = hsv[2], hv3 = hsv[3];
        float c0 = p0, c1 = p1, c2 = p2;
        if (g < 64 && m + 1 < HP) {
            const float* gp = gi + (size_t)(m + 1) * 192;
            p0 = gp[g]; p1 = gp[64 + g]; p2 = gp[128 + g];
        }
        float a0 = 0.f, a1 = 0.f, a2 = 0.f, a3 = 0.f;
        DOT8(w0, hv0, a0)
        DOT8(w1, hv1, a1)
        DOT8(w2, hv2, a2)
        DOT8(w3, hv3, a3)
        float a = (a0 + a1) + (a2 + a3) + bh;
        Ax[g] = a;
        LGKM_BARRIER();                       // Ax visible; no vmcnt drain
        if (g < 64) {
            float az = Ax[64 + g], an = Ax[128 + g];
            float rg = 1.f / (1.f + __expf(-(c0 + a)));
            float zg = 1.f / (1.f + __expf(-(c1 + az)));
            float pre = c2 + rg * an;
            float ex = __expf(2.f * pre);
            float nn = 1.f - 2.f / (ex + 1.f);      // tanh, overflow-safe
            h = (1.f - zg) * nn + zg * h;
            hs[g] = (_Float16)h;
            out[(size_t)m * 64 + g] = h;            // store stays in flight
        }
        LGKM_BARRIER();                       // h visible; no vmcnt drain
    }
#undef DOT8
#undef LGKM_BARRIER
}

// ---------------- alignment column stats (online softmax over m) ----------
__global__ __launch_bounds__(256) void astat_k(const float* __restrict__ e,
        const float* __restrict__ t, float* __restrict__ pM,
        float* __restrict__ pZ) {
    __shared__ alignas(16) float Ts[64][68];
    __shared__ float Ms[4][64], Zs[4][64];
    int tid = threadIdx.x;
    int nl = tid & 63, ms = tid >> 6;
    int n0 = blockIdx.x * 64;
#pragma unroll
    for (int i = 0; i < 16; i++) {
        int idx = tid + i * 256;
        int rr = idx >> 6, kk = idx & 63;
        int n = n0 + rr;
        Ts[rr][kk] = (n < HP) ? t[(size_t)n * 64 + kk] : 0.f;
    }
    __syncthreads();
    float M = -1e30f, Z = 0.f;
    int m0 = blockIdx.y * 510;
    const float4* Trow = (const float4*)&Ts[nl][0];
    for (int m = m0 + ms; m < m0 + 510; m += 4) {
        const float4* er = (const float4*)(e + (size_t)m * 64);
        float a0 = 0, a1 = 0, a2 = 0, a3 = 0;
#pragma unroll
        for (int i = 0; i < 16; i++) {
            float4 evv = er[i], tv = Trow[i];
            a0 = fmaf(evv.x, tv.x, a0); a1 = fmaf(evv.y, tv.y, a1);
            a2 = fmaf(evv.z, tv.z, a2); a3 = fmaf(evv.w, tv.w, a3);
        }
        float s = (a0 + a1) + (a2 + a3);
        float nM = fmaxf(M, s);
        Z = Z * __expf(M - nM) + __expf(s - nM);
        M = nM;
    }
    Ms[ms][nl] = M; Zs[ms][nl] = Z;
    __syncthreads();
    if (ms == 0) {
#pragma unroll
        for (int i = 1; i < 4; i++) {
            float m2 = Ms[i][nl], z2 = Zs[i][nl];
            float nM = fmaxf(M, m2);
            Z = Z * __expf(M - nM) + z2 * __expf(m2 - nM);
            M = nM;
        }
        int n = n0 + nl;
        if (n < HP) { pM[(size_t)blockIdx.y * HP + n] = M; pZ[(size_t)blockIdx.y * HP + n] = Z; }
    }
}

// ---------------- attention logits ----------------
__global__ __launch_bounds__(256) void attnlog_k(const float* __restrict__ e,
        const float* __restrict__ aw, const float* __restrict__ ab,
        float* __restrict__ alog) {
    int m = blockIdx.x * 256 + threadIdx.x;
    if (m >= HP) return;
    float acc = ab[0];
    const float4* er = (const float4*)(e + (size_t)m * 64);
    const float4* ar = (const float4*)aw;
#pragma unroll
    for (int i = 0; i < 16; i++) {
        float4 evv = er[i], av = ar[i];
        acc += evv.x * av.x + evv.y * av.y + evv.z * av.z + evv.w * av.w;
    }
    alog[m] = acc;
}

// ---------------- reduce partial stats + attn softmax stats ---------------
__global__ __launch_bounds__(256) void reduce_k(const float* __restrict__ pM,
        const float* __restrict__ pZ, float* __restrict__ Mn,
        float* __restrict__ Zn, const float* __restrict__ alog,
        float* __restrict__ scal) {
    int tid = threadIdx.x;
    if (blockIdx.x < 16) {
        int n = blockIdx.x * 256 + tid;
        if (n >= HP) return;
        float M = pM[n], Z = pZ[n];
#pragma unroll
        for (int y = 1; y < 8; y++) {
            float m2 = pM[(size_t)y * HP + n], z2 = pZ[(size_t)y * HP + n];
            float nM = fmaxf(M, m2);
            Z = Z * __expf(M - nM) + z2 * __expf(m2 - nM);
            M = nM;
        }
        Mn[n] = M; Zn[n] = Z;
    } else {
        __shared__ float red[256];
        float m = -1e30f;
        for (int i = tid; i < HP; i += 256) m = fmaxf(m, alog[i]);
        red[tid] = m; __syncthreads();
        for (int s = 128; s > 0; s >>= 1) {
            if (tid < s) red[tid] = fmaxf(red[tid], red[tid + s]);
            __syncthreads();
        }
        float Ma = red[0]; __syncthreads();
        float z = 0.f;
        for (int i = tid; i < HP; i += 256) z += __expf(alog[i] - Ma);
        red[tid] = z; __syncthreads();
        for (int s = 128; s > 0; s >>= 1) {
            if (tid < s) red[tid] += red[tid + s];
            __syncthreads();
        }
        if (tid == 0) { scal[0] = Ma; scal[1] = red[0]; }
    }
}

// ---------------- Wmat rows m<64 ----------------
__global__ __launch_bounds__(256) void wmat_k(const float* __restrict__ e,
        const float* __restrict__ t, const float* __restrict__ Mn,
        const float* __restrict__ Zn, float* __restrict__ Wm) {
    __shared__ alignas(16) float Es[64][68];
    int tid = threadIdx.x;
#pragma unroll
    for (int i = 0; i < 16; i++) {
        int idx = tid + i * 256;
        int rr = idx >> 6, kk = idx & 63;
        Es[rr][kk] = e[(size_t)rr * 64 + kk];
    }
    __syncthreads();
    int n = blockIdx.x * 256 + tid;
    if (n >= HP) return;
    float tn[64];
    const float4* tr = (const float4*)(t + (size_t)n * 64);
    float4* tn4 = (float4*)tn;
#pragma unroll
    for (int i = 0; i < 16; i++) tn4[i] = tr[i];
    float mM = Mn[n], iZ = 1.f / Zn[n];
#pragma unroll 1
    for (int m = 0; m < 64; m++) {
        const float4* Er = (const float4*)&Es[m][0];
        float a0 = 0, a1 = 0, a2 = 0, a3 = 0;
#pragma unroll
        for (int i = 0; i < 16; i++) {
            float4 evv = Er[i], tv = tn4[i];
            a0 = fmaf(evv.x, tv.x, a0); a1 = fmaf(evv.y, tv.y, a1);
            a2 = fmaf(evv.z, tv.z, a2); a3 = fmaf(evv.w, tv.w, a3);
        }
        float s = (a0 + a1) + (a2 + a3);
        Wm[(size_t)m * HP + n] = __expf(s - mM) * iZ;
    }
}

// ---------------- t_prim = Wm(64 x 4080) @ t(4080 x 64), K-split atomics ---
__global__ __launch_bounds__(256) void tprim_k(const float* __restrict__ Wm,
        const float* __restrict__ t, float* __restrict__ tp) {
    __shared__ float Ws[64][64];
    __shared__ float Ts[64][64];
    int tid = threadIdx.x;
    int n0 = blockIdx.x * 64;
#pragma unroll
    for (int i = 0; i < 16; i++) {
        int idx = tid + i * 256;
        int r = idx >> 6, c = idx & 63;
        Ws[r][c] = (n0 + c < HP) ? Wm[(size_t)r * HP + n0 + c] : 0.f;
        Ts[r][c] = (n0 + r < HP) ? t[(size_t)(n0 + r) * 64 + c] : 0.f;
    }
    __syncthreads();
    int d = tid & 63, mg = tid >> 6;
    float acc[16];
#pragma unroll
    for (int i = 0; i < 16; i++) acc[i] = 0.f;
    for (int k = 0; k < 64; k++) {
        float tv = Ts[k][d];
#pragma unroll
        for (int mm = 0; mm < 16; mm++) acc[mm] = fmaf(Ws[mg * 16 + mm][k], tv, acc[mm]);
    }
#pragma unroll
    for (int mm = 0; mm < 16; mm++)
        atomicAdd(&tp[(size_t)(mg * 16 + mm) * 64 + d], acc[mm]);
}

// ---------------- epilogue ----------------
__global__ __launch_bounds__(256) void final_k(const float* __restrict__ tp,
        const float* __restrict__ e, const float* __restrict__ alog,
        const float* __restrict__ scal, const float* __restrict__ l3w,
        const float* __restrict__ l3b, const float* __restrict__ cw,
        const float* __restrict__ cb, float* __restrict__ out) {
    __shared__ float r1[64], hid[128];
    int tid = threadIdx.x;
    float Ma = scal[0], iZa = 1.f / scal[1];
    if (tid < 64) {
        float acc = 0.f;
        for (int m = 0; m < 64; m++) {
            float a = __expf(alog[m] - Ma) * iZa;
            acc += fabsf(tp[m * 64 + tid] - e[m * 64 + tid]) * a;
        }
        r1[tid] = fmaxf(acc, 0.f);
    }
    __syncthreads();
    if (tid < 128) {
        float acc = l3b[tid];
        for (int d = 0; d < 64; d++) acc = fmaf(r1[d], l3w[tid * 64 + d], acc);
        hid[tid] = fmaxf(acc, 0.f);
    }
    __syncthreads();
    if (tid < 2) {
        float acc = cb[tid];
        for (int j = 0; j < 128; j++) acc = fmaf(hid[j], cw[tid * 128 + j], acc);
        out[tid] = acc;
    }
}

// ---------------- weight packing ----------------
__global__ __launch_bounds__(256) void transpose_l1w_k(const float* __restrict__ w,
        float* __restrict__ wt) {
    int idx = blockIdx.x * 256 + threadIdx.x;
    if (idx >= KF * 64) return;
    int k = idx >> 6, j = idx & 63;
    wt[idx] = w[(size_t)j * KF + k];
}
__global__ __launch_bounds__(256) void pack_w1_k(const float* __restrict__ w,
        float* __restrict__ wp) {
    int idx = blockIdx.x * 256 + threadIdx.x;
    if (idx >= 400) return;
    int k = idx >> 4, co = idx & 15;
    wp[idx] = w[co * 25 + k];
}
// conv2 dot2 pack: entry (ci,q,co) -> half2 (taps 2q, 2q+1; pad 0)
__global__ __launch_bounds__(256) void pack_w2p_k(const float* __restrict__ w,
        _Float16* __restrict__ wp2) {
    int idx = blockIdx.x * 256 + threadIdx.x;
    if (idx >= 16 * 13 * 32) return;
    int co = idx & 31; int rest = idx >> 5;
    int q = rest % 13, ci = rest / 13;
    int t0 = 2 * q, t1 = 2 * q + 1;
    float v0 = (t0 < 25) ? w[co * 400 + ci * 25 + t0] : 0.f;
    float v1 = (t1 < 25) ? w[co * 400 + ci * 25 + t1] : 0.f;
    wp2[(size_t)idx * 2 + 0] = (_Float16)v0;
    wp2[(size_t)idx * 2 + 1] = (_Float16)v1;
}
// conv3 dot2 pack: entry (ci,q,co), co<64
__global__ __launch_bounds__(256) void pack_w3p_k(const float* __restrict__ w,
        _Float16* __restrict__ wp2) {
    int idx = blockIdx.x * 256 + threadIdx.x;
    if (idx >= 32 * 13 * 64) return;
    int co = idx & 63; int rest = idx >> 6;
    int q = rest % 13, ci = rest / 13;
    int t0 = 2 * q, t1 = 2 * q + 1;
    float v0 = (t0 < 25) ? w[co * 800 + ci * 25 + t0] : 0.f;
    float v1 = (t1 < 25) ? w[co * 800 + ci * 25 + t1] : 0.f;
    wp2[(size_t)idx * 2 + 0] = (_Float16)v0;
    wp2[(size_t)idx * 2 + 1] = (_Float16)v1;
}
__global__ __launch_bounds__(256) void pack_wih_k(const float* __restrict__ wih,
        const float* __restrict__ bih, const float* __restrict__ l1b,
        const float* __restrict__ whh, float* __restrict__ wiht,
        float* __restrict__ bc, _Float16* __restrict__ whh_h) {
    int idx = blockIdx.x * 256 + threadIdx.x;
    if (idx < 12288) {
        int g = idx % 192, k = idx / 192;
        wiht[idx] = wih[g * 64 + k];
        whh_h[idx] = (_Float16)whh[idx];
    }
    if (idx < 192) {
        float acc = bih[idx];
#pragma unroll
        for (int k = 0; k < 64; k++) acc = fmaf(wih[idx * 64 + k], l1b[k], acc);
        bc[idx] = acc;
    }
}

// ---------------- host ----------------
extern "C" void kernel_launch(void* const* d_in, const int* in_sizes, int n_in,
                              void* d_out, int out_size, void* d_ws, size_t ws_size,
                              hipStream_t stream) {
    const float* ev    = (const float*)d_in[0];
    const float* tmpl  = (const float*)d_in[1];
    const float* w1    = (const float*)d_in[2];
    const float* b1    = (const float*)d_in[3];
    const float* w2    = (const float*)d_in[4];
    const float* b2    = (const float*)d_in[5];
    const float* w3    = (const float*)d_in[6];
    const float* b3    = (const float*)d_in[7];
    const float* l1w   = (const float*)d_in[8];
    const float* l1b   = (const float*)d_in[9];
    const float* wih   = (const float*)d_in[10];
    const float* whh   = (const float*)d_in[11];
    const float* bih   = (const float*)d_in[12];
    const float* bhh   = (const float*)d_in[13];
    const float* aw    = (const float*)d_in[14];
    const float* ab    = (const float*)d_in[15];
    const float* l3w   = (const float*)d_in[16];
    const float* l3b   = (const float*)d_in[17];
    const float* cw    = (const float*)d_in[18];
    const float* cb    = (const float*)d_in[19];
    float* out = (float*)d_out;
    (void)in_sizes; (void)n_in; (void)out_size;

    char* ws = (char*)d_ws;
    size_t off = 0;
    auto alloc = [&](size_t bytes) -> char* {
        char* p = ws + off;
        off += (bytes + 255) & ~(size_t)255;
        return p;
    };
    size_t szA = (size_t)C3 * H3 * W3 * 2;                 // fp16 conv3 out (> conv1 out fp16)
    char*  A    = alloc(szA);
    float* B    = (float*)alloc((size_t)HP * KF * 4);      // conv2 fp16 out / pooled fp32
    float* Wt   = (float*)alloc((size_t)KF * 64 * 4);
    float* w1p  = (float*)alloc(400 * 4);
    _Float16* w2p2 = (_Float16*)alloc(16 * 13 * 32 * 2 * 2);
    _Float16* w3p2 = (_Float16*)alloc(32 * 13 * 64 * 2 * 2);
    float* wiht = (float*)alloc(12288 * 4);
    _Float16* whhh = (_Float16*)alloc(12288 * 2);
    float* bc   = (float*)alloc(256 * 4);
    float* L    = (float*)alloc((size_t)HP * 64 * 4);
    float* gi0  = (float*)alloc((size_t)HP * 192 * 4);
    float* gi1  = (float*)alloc((size_t)HP * 192 * 4);
    float* ebuf = (float*)alloc((size_t)HP * 64 * 4);
    float* tbuf = (float*)alloc((size_t)HP * 64 * 4);
    float* pM   = (float*)alloc((size_t)8 * HP * 4);
    float* pZ   = (float*)alloc((size_t)8 * HP * 4);
    float* Mn   = (float*)alloc(HP * 4);
    float* Zn   = (float*)alloc(HP * 4);
    float* Wm   = (float*)alloc((size_t)64 * HP * 4);
    float* alog = (float*)alloc(HP * 4);
    float* tpm  = (float*)alloc(64 * 64 * 4);
    float* scal = (float*)alloc(256);
    if (off > ws_size) return;   // workspace too small: bail loudly (validation fails)

    transpose_l1w_k<<<dim3((KF * 64 + 255) / 256), dim3(256), 0, stream>>>(l1w, Wt);
    pack_w1_k<<<dim3(2), dim3(256), 0, stream>>>(w1, w1p);
    pack_w2p_k<<<dim3((16 * 13 * 32 + 255) / 256), dim3(256), 0, stream>>>(w2, w2p2);
    pack_w3p_k<<<dim3((32 * 13 * 64 + 255) / 256), dim3(256), 0, stream>>>(w3, w3p2);
    pack_wih_k<<<dim3(48), dim3(256), 0, stream>>>(wih, bih, l1b, whh, wiht, bc, whhh);

    for (int bsel = 0; bsel < 2; bsel++) {
        const float* xin = bsel ? tmpl : ev;
        float* gib = bsel ? gi1 : gi0;
        conv1_k<<<dim3((H1 * W1 + 255) / 256), dim3(256), 0, stream>>>(xin, w1p, b1, (__half*)A);
        conv2_k<<<dim3(2, (H2 * W2 + 255) / 256), dim3(256), 0, stream>>>((const __half*)A, w2p2, b2, (__half*)B);
        conv3_k<<<dim3(4, (H3 * W3 + 255) / 256), dim3(256), 0, stream>>>((const __half*)B, w3p2, b3, (__half*)A);
        pool_k<<<dim3((C3 * HP * WPW + 255) / 256), dim3(256), 0, stream>>>((const __half*)A, B);
        hipMemsetAsync(L, 0, (size_t)HP * 64 * 4, stream);
        lin1_k<<<dim3(64, 4), dim3(256), 0, stream>>>(B, Wt, L);
        gi_k<<<dim3(HP / 8), dim3(192), 0, stream>>>(L, wiht, bc, gib);
    }
    gru_k<<<dim3(2), dim3(192), 0, stream>>>(gi0, gi1, whhh, bhh, ebuf, tbuf);
    astat_k<<<dim3(64, 8), dim3(256), 0, stream>>>(ebuf, tbuf, pM, pZ);
    attnlog_k<<<dim3(16), dim3(256), 0, stream>>>(ebuf, aw, ab, alog);
    reduce_k<<<dim3(17), dim3(256), 0, stream>>>(pM, pZ, Mn, Zn, alog, scal);
    wmat_k<<<dim3(16), dim3(256), 0, stream>>>(ebuf, tbuf, Mn, Zn, Wm);
    hipMemsetAsync(tpm, 0, 64 * 64 * 4, stream);
    tprim_k<<<dim3(64), dim3(256), 0, stream>>>(Wm, tbuf, tpm);
    final_k<<<dim3(1), dim3(256), 0, stream>>>(tpm, ebuf, alog, scal, l3w, l3b, cw, cb, out);
}

// Round 21
// 3392.507 us; speedup vs baseline: 1.2354x; 1.0833x over previous
//
#include <hip/hip_runtime.h>
#include <hip/hip_fp16.h>

// ---------------- dimensions ----------------
constexpr int T_IN = 4096, W_IN = 128;
constexpr int H1 = 4092, W1 = 124, C1 = 16;
constexpr int H2 = 4088, W2 = 120, C2 = 32;
constexpr int H3 = 4084, W3 = 116, C3 = 64;
constexpr int HP = 4080, WPW = 58;      // pooled
constexpr int KF = 3712;                // 64*58 flattened features

typedef float f32x16 __attribute__((ext_vector_type(16)));
typedef _Float16 f16x16 __attribute__((ext_vector_type(16)));
typedef _Float16 half2_t __attribute__((ext_vector_type(2)));

static __device__ __forceinline__ half2_t u2h(unsigned int u) {
    half2_t h; __builtin_memcpy(&h, &u, 4); return h;
}

// 25 fp32 input taps as NAMED scalars
#define LOAD25(SRC, W) \
    float p00=(SRC)[0],        p01=(SRC)[1],        p02=(SRC)[2],        p03=(SRC)[3],        p04=(SRC)[4]; \
    float p10=(SRC)[(W)],      p11=(SRC)[(W)+1],    p12=(SRC)[(W)+2],    p13=(SRC)[(W)+3],    p14=(SRC)[(W)+4]; \
    float p20=(SRC)[2*(W)],    p21=(SRC)[2*(W)+1],  p22=(SRC)[2*(W)+2],  p23=(SRC)[2*(W)+3],  p24=(SRC)[2*(W)+4]; \
    float p30=(SRC)[3*(W)],    p31=(SRC)[3*(W)+1],  p32=(SRC)[3*(W)+2],  p33=(SRC)[3*(W)+3],  p34=(SRC)[3*(W)+4]; \
    float p40=(SRC)[4*(W)],    p41=(SRC)[4*(W)+1],  p42=(SRC)[4*(W)+2],  p43=(SRC)[4*(W)+3],  p44=(SRC)[4*(W)+4];

#define TAPS25(T) \
    T(p00, 0)  T(p01, 1)  T(p02, 2)  T(p03, 3)  T(p04, 4) \
    T(p10, 5)  T(p11, 6)  T(p12, 7)  T(p13, 8)  T(p14, 9) \
    T(p20,10)  T(p21,11)  T(p22,12)  T(p23,13)  T(p24,14) \
    T(p30,15)  T(p31,16)  T(p32,17)  T(p33,18)  T(p34,19) \
    T(p40,20)  T(p41,21)  T(p42,22)  T(p43,23)  T(p44,24)

// 16 FMAs into 4 named float4 accumulators (fp32 path, conv1)
#define KSTEP16(PK, WPTR) do { \
    const float4* w4_ = (const float4*)(WPTR); \
    float4 wA_ = w4_[0], wB_ = w4_[1], wC_ = w4_[2], wD_ = w4_[3]; \
    a0.x = fmaf((PK), wA_.x, a0.x); a0.y = fmaf((PK), wA_.y, a0.y); \
    a0.z = fmaf((PK), wA_.z, a0.z); a0.w = fmaf((PK), wA_.w, a0.w); \
    a1.x = fmaf((PK), wB_.x, a1.x); a1.y = fmaf((PK), wB_.y, a1.y); \
    a1.z = fmaf((PK), wB_.z, a1.z); a1.w = fmaf((PK), wB_.w, a1.w); \
    a2.x = fmaf((PK), wC_.x, a2.x); a2.y = fmaf((PK), wC_.y, a2.y); \
    a2.z = fmaf((PK), wC_.z, a2.z); a2.w = fmaf((PK), wC_.w, a2.w); \
    a3.x = fmaf((PK), wD_.x, a3.x); a3.y = fmaf((PK), wD_.y, a3.y); \
    a3.z = fmaf((PK), wD_.z, a3.z); a3.w = fmaf((PK), wD_.w, a3.w); \
} while (0)

// 25 fp16 taps as NAMED scalars
#define LOAD25H(SRC, W) \
    _Float16 q00=(_Float16)(SRC)[0],      q01=(_Float16)(SRC)[1],      q02=(_Float16)(SRC)[2],      q03=(_Float16)(SRC)[3],      q04=(_Float16)(SRC)[4]; \
    _Float16 q10=(_Float16)(SRC)[(W)],    q11=(_Float16)(SRC)[(W)+1],  q12=(_Float16)(SRC)[(W)+2],  q13=(_Float16)(SRC)[(W)+3],  q14=(_Float16)(SRC)[(W)+4]; \
    _Float16 q20=(_Float16)(SRC)[2*(W)],  q21=(_Float16)(SRC)[2*(W)+1],q22=(_Float16)(SRC)[2*(W)+2],q23=(_Float16)(SRC)[2*(W)+3],q24=(_Float16)(SRC)[2*(W)+4]; \
    _Float16 q30=(_Float16)(SRC)[3*(W)],  q31=(_Float16)(SRC)[3*(W)+1],q32=(_Float16)(SRC)[3*(W)+2],q33=(_Float16)(SRC)[3*(W)+3],q34=(_Float16)(SRC)[3*(W)+4]; \
    _Float16 q40=(_Float16)(SRC)[4*(W)],  q41=(_Float16)(SRC)[4*(W)+1],q42=(_Float16)(SRC)[4*(W)+2],q43=(_Float16)(SRC)[4*(W)+3],q44=(_Float16)(SRC)[4*(W)+4];

// 13 tap pairs (row-major tap order, last padded with 0)
#define MKPAIRS() \
    half2_t P0, P1, P2, P3, P4, P5, P6, P7, P8, P9, P10, P11, P12; \
    P0[0]=q00; P0[1]=q01;  P1[0]=q02; P1[1]=q03;  P2[0]=q04; P2[1]=q10; \
    P3[0]=q11; P3[1]=q12;  P4[0]=q13; P4[1]=q14;  P5[0]=q20; P5[1]=q21; \
    P6[0]=q22; P6[1]=q23;  P7[0]=q24; P7[1]=q30;  P8[0]=q31; P8[1]=q32; \
    P9[0]=q33; P9[1]=q34;  P10[0]=q40; P10[1]=q41; P11[0]=q42; P11[1]=q43; \
    P12[0]=q44; P12[1]=(_Float16)0.f;

// 16 dot2 into 4 named float4 accumulators; WPTR = half2_t* (16 entries)
#define DSTEP16(PH, WPTR) do { \
    const half2_t* wv_ = (const half2_t*)(WPTR); \
    a0.x = __builtin_amdgcn_fdot2((PH), wv_[0],  a0.x, false); \
    a0.y = __builtin_amdgcn_fdot2((PH), wv_[1],  a0.y, false); \
    a0.z = __builtin_amdgcn_fdot2((PH), wv_[2],  a0.z, false); \
    a0.w = __builtin_amdgcn_fdot2((PH), wv_[3],  a0.w, false); \
    a1.x = __builtin_amdgcn_fdot2((PH), wv_[4],  a1.x, false); \
    a1.y = __builtin_amdgcn_fdot2((PH), wv_[5],  a1.y, false); \
    a1.z = __builtin_amdgcn_fdot2((PH), wv_[6],  a1.z, false); \
    a1.w = __builtin_amdgcn_fdot2((PH), wv_[7],  a1.w, false); \
    a2.x = __builtin_amdgcn_fdot2((PH), wv_[8],  a2.x, false); \
    a2.y = __builtin_amdgcn_fdot2((PH), wv_[9],  a2.y, false); \
    a2.z = __builtin_amdgcn_fdot2((PH), wv_[10], a2.z, false); \
    a2.w = __builtin_amdgcn_fdot2((PH), wv_[11], a2.w, false); \
    a3.x = __builtin_amdgcn_fdot2((PH), wv_[12], a3.x, false); \
    a3.y = __builtin_amdgcn_fdot2((PH), wv_[13], a3.y, false); \
    a3.z = __builtin_amdgcn_fdot2((PH), wv_[14], a3.z, false); \
    a3.w = __builtin_amdgcn_fdot2((PH), wv_[15], a3.w, false); \
} while (0)

#define PAIRS13(D, CI) \
    D(P0,  ((CI)*13+ 0)) D(P1,  ((CI)*13+ 1)) D(P2,  ((CI)*13+ 2)) \
    D(P3,  ((CI)*13+ 3)) D(P4,  ((CI)*13+ 4)) D(P5,  ((CI)*13+ 5)) \
    D(P6,  ((CI)*13+ 6)) D(P7,  ((CI)*13+ 7)) D(P8,  ((CI)*13+ 8)) \
    D(P9,  ((CI)*13+ 9)) D(P10, ((CI)*13+10)) D(P11, ((CI)*13+11)) \
    D(P12, ((CI)*13+12))

// ---------------- conv1: 1 -> 16, fp32 math, fp16 out ---------------------
__global__ __launch_bounds__(256, 2) void conv1_k(const float* __restrict__ x,
        const float* __restrict__ wp, const float* __restrict__ b,
        __half* __restrict__ out) {
    int pos = blockIdx.x * 256 + threadIdx.x;
    if (pos >= H1 * W1) return;
    int h = pos / W1, wi = pos - h * W1;
    const float* src = x + h * W_IN + wi;
    const float4* b4 = (const float4*)b;
    float4 a0 = b4[0], a1 = b4[1], a2 = b4[2], a3 = b4[3];
    LOAD25(src, W_IN);
#define T1(P, K) KSTEP16(P, wp + (K) * 16);
    TAPS25(T1)
#undef T1
#pragma unroll
    for (int i = 0; i < 4; i++) {
        float4 v = (i == 0) ? a0 : (i == 1) ? a1 : (i == 2) ? a2 : a3;
        out[(size_t)(i * 4 + 0) * (H1 * W1) + pos] = __float2half(v.x);
        out[(size_t)(i * 4 + 1) * (H1 * W1) + pos] = __float2half(v.y);
        out[(size_t)(i * 4 + 2) * (H1 * W1) + pos] = __float2half(v.z);
        out[(size_t)(i * 4 + 3) * (H1 * W1) + pos] = __float2half(v.w);
    }
}

// ---------------- conv2: 16 -> 32, fp16 dot2; co-group = blockIdx.x -------
__global__ __launch_bounds__(256, 2) void conv2_k(const __half* __restrict__ in,
        const _Float16* __restrict__ wp2, const float* __restrict__ b,
        __half* __restrict__ out) {
    int pos = blockIdx.y * 256 + threadIdx.x;
    if (pos >= H2 * W2) return;
    int co0 = blockIdx.x * 16;
    int h = pos / W2, wi = pos - h * W2;
    const float4* b4 = (const float4*)(b + co0);
    float4 a0 = b4[0], a1 = b4[1], a2 = b4[2], a3 = b4[3];
#pragma unroll 1
    for (int ci = 0; ci < C1; ci++) {
        const __half* src = in + (size_t)ci * (H1 * W1) + h * W1 + wi;
        LOAD25H(src, W1);
        MKPAIRS();
#define D2(PH, QI) DSTEP16(PH, wp2 + ((size_t)(QI) * C2 + co0) * 2);
        PAIRS13(D2, ci)
#undef D2
    }
#pragma unroll
    for (int i = 0; i < 4; i++) {
        float4 v = (i == 0) ? a0 : (i == 1) ? a1 : (i == 2) ? a2 : a3;
        out[(size_t)(co0 + i * 4 + 0) * (H2 * W2) + pos] = __float2half(v.x);
        out[(size_t)(co0 + i * 4 + 1) * (H2 * W2) + pos] = __float2half(v.y);
        out[(size_t)(co0 + i * 4 + 2) * (H2 * W2) + pos] = __float2half(v.z);
        out[(size_t)(co0 + i * 4 + 3) * (H2 * W2) + pos] = __float2half(v.w);
    }
}

// ---------------- conv3: 32 -> 64, fp16 dot2; co-group = blockIdx.x -------
__global__ __launch_bounds__(256, 2) void conv3_k(const __half* __restrict__ in,
        const _Float16* __restrict__ wp2, const float* __restrict__ b,
        __half* __restrict__ out) {
    int pos = blockIdx.y * 256 + threadIdx.x;
    if (pos >= H3 * W3) return;
    int co0 = blockIdx.x * 16;
    int h = pos / W3, wi = pos - h * W3;
    const float4* b4 = (const float4*)(b + co0);
    float4 a0 = b4[0], a1 = b4[1], a2 = b4[2], a3 = b4[3];
#pragma unroll 1
    for (int ci = 0; ci < C2; ci++) {
        const __half* src = in + (size_t)ci * (H2 * W2) + h * W2 + wi;
        LOAD25H(src, W2);
        MKPAIRS();
#define D3(PH, QI) DSTEP16(PH, wp2 + ((size_t)(QI) * C3 + co0) * 2);
        PAIRS13(D3, ci)
#undef D3
    }
#pragma unroll
    for (int i = 0; i < 4; i++) {
        float4 v = (i == 0) ? a0 : (i == 1) ? a1 : (i == 2) ? a2 : a3;
        out[(size_t)(co0 + i * 4 + 0) * (H3 * W3) + pos] = __float2half(v.x);
        out[(size_t)(co0 + i * 4 + 1) * (H3 * W3) + pos] = __float2half(v.y);
        out[(size_t)(co0 + i * 4 + 2) * (H3 * W3) + pos] = __float2half(v.z);
        out[(size_t)(co0 + i * 4 + 3) * (H3 * W3) + pos] = __float2half(v.w);
    }
}

// ---------------- maxpool 5x2 stride 1,2 -> fp16 out ----------------------
__global__ __launch_bounds__(256) void pool_k(const __half* __restrict__ in,
        _Float16* __restrict__ out) {
    int idx = blockIdx.x * 256 + threadIdx.x;
    if (idx >= C3 * HP * WPW) return;
    int w = idx % WPW; int rest = idx / WPW; int h = rest % HP; int c = rest / HP;
    const __half* base = in + (size_t)c * (H3 * W3) + (size_t)h * W3 + 2 * w;
    float m = -1e30f;
#pragma unroll
    for (int i = 0; i < 5; i++)
#pragma unroll
        for (int j = 0; j < 2; j++)
            m = fmaxf(m, __half2float(base[(size_t)i * W3 + j]));
    out[idx] = (_Float16)m;   // layout == flat view (HP, 3712)
}

// ---------------- lin1: fp16 dot2, (4080 x 3712) @ Wt2, K-split + atomics -
// X fp16, weights as half2 K-pairs: Wt2[(kk)*64 + j] = (W[2kk][j], W[2kk+1][j])
__global__ __launch_bounds__(256, 2) void lin1_k(const _Float16* __restrict__ X,
        const _Float16* __restrict__ Wt2, float* __restrict__ L) {
    __shared__ unsigned int Xs[32][68];   // half2-packed K-pairs x 64 m
    int tid = threadIdx.x;
    int j = tid & 63, mg = tid >> 6;
    int m0 = blockIdx.x * 64;
    int c0 = blockIdx.y * 15;
    int c1 = (c0 + 15 < 58) ? c0 + 15 : 58;
    float4 la0 = {0.f,0.f,0.f,0.f}, la1 = la0, la2 = la0, la3 = la0;
    for (int cc = c0; cc < c1; cc++) {
        int k0 = cc * 64, kp0 = cc * 32;
        __syncthreads();
#pragma unroll
        for (int t = 0; t < 8; t++) {
            int idx = tid + t * 256;          // 0..2047
            int mm = idx >> 5, kk = idx & 31;
            int m = m0 + mm;
            unsigned int v = 0;
            if (m < HP) v = *(const unsigned int*)(X + (size_t)m * KF + k0 + 2 * kk);
            Xs[kk][mm] = v;
        }
        __syncthreads();
#pragma unroll 4
        for (int kk = 0; kk < 32; kk++) {
            unsigned int wvu = *(const unsigned int*)(Wt2 + ((size_t)(kp0 + kk) * 64 + j) * 2);
            half2_t wv = u2h(wvu);
            const uint4* xr = (const uint4*)&Xs[kk][mg * 16];
            uint4 x0 = xr[0], x1 = xr[1], x2 = xr[2], x3 = xr[3];
            la0.x = __builtin_amdgcn_fdot2(u2h(x0.x), wv, la0.x, false);
            la0.y = __builtin_amdgcn_fdot2(u2h(x0.y), wv, la0.y, false);
            la0.z = __builtin_amdgcn_fdot2(u2h(x0.z), wv, la0.z, false);
            la0.w = __builtin_amdgcn_fdot2(u2h(x0.w), wv, la0.w, false);
            la1.x = __builtin_amdgcn_fdot2(u2h(x1.x), wv, la1.x, false);
            la1.y = __builtin_amdgcn_fdot2(u2h(x1.y), wv, la1.y, false);
            la1.z = __builtin_amdgcn_fdot2(u2h(x1.z), wv, la1.z, false);
            la1.w = __builtin_amdgcn_fdot2(u2h(x1.w), wv, la1.w, false);
            la2.x = __builtin_amdgcn_fdot2(u2h(x2.x), wv, la2.x, false);
            la2.y = __builtin_amdgcn_fdot2(u2h(x2.y), wv, la2.y, false);
            la2.z = __builtin_amdgcn_fdot2(u2h(x2.z), wv, la2.z, false);
            la2.w = __builtin_amdgcn_fdot2(u2h(x2.w), wv, la2.w, false);
            la3.x = __builtin_amdgcn_fdot2(u2h(x3.x), wv, la3.x, false);
            la3.y = __builtin_amdgcn_fdot2(u2h(x3.y), wv, la3.y, false);
            la3.z = __builtin_amdgcn_fdot2(u2h(x3.z), wv, la3.z, false);
            la3.w = __builtin_amdgcn_fdot2(u2h(x3.w), wv, la3.w, false);
        }
    }
    int mb = m0 + mg * 16;
#define LATOM(C, OFF) { int m = mb + (OFF); if (m < HP) atomicAdd(&L[(size_t)m * 64 + j], (C)); }
    LATOM(la0.x, 0)  LATOM(la0.y, 1)  LATOM(la0.z, 2)  LATOM(la0.w, 3)
    LATOM(la1.x, 4)  LATOM(la1.y, 5)  LATOM(la1.z, 6)  LATOM(la1.w, 7)
    LATOM(la2.x, 8)  LATOM(la2.y, 9)  LATOM(la2.z, 10) LATOM(la2.w, 11)
    LATOM(la3.x, 12) LATOM(la3.y, 13) LATOM(la3.z, 14) LATOM(la3.w, 15)
#undef LATOM
}

// ---------------- gi = L @ wih^T + bc, 8 rows per block -------------------
__global__ __launch_bounds__(192) void gi_k(const float* __restrict__ L,
        const float* __restrict__ wiht, const float* __restrict__ bc,
        float* __restrict__ gi) {
    __shared__ alignas(16) float Ls[8][64];
    int m0 = blockIdx.x * 8, g = threadIdx.x;
    for (int idx = g; idx < 512; idx += 192) {
        int r = idx >> 6, k = idx & 63;
        Ls[r][k] = L[(size_t)(m0 + r) * 64 + k];
    }
    __syncthreads();
    float bcv = bc[g];
#pragma unroll 1
    for (int r = 0; r < 8; r++) {
        float acc = bcv;
#pragma unroll
        for (int k = 0; k < 64; k++) acc = fmaf(Ls[r][k], wiht[k * 192 + g], acc);
        gi[(size_t)(m0 + r) * 192 + g] = acc;
    }
}

// ---------------- GRU: 3 waves, 2 lgkm barriers, fp16 dot2 (best) ---------
__global__ __launch_bounds__(192, 1) void gru_k(const float* __restrict__ gi0,
        const float* __restrict__ gi1, const _Float16* __restrict__ whh_h,
        const float* __restrict__ bhh, float* __restrict__ e,
        float* __restrict__ t) {
    const float* gi = blockIdx.x ? gi1 : gi0;
    float* out = blockIdx.x ? t : e;
    const int g = threadIdx.x;           // gate row, 0..191
    const f16x16* wp = (const f16x16*)(whh_h + (size_t)g * 64);
    f16x16 w0 = wp[0], w1 = wp[1], w2 = wp[2], w3 = wp[3];
    float bh = bhh[g];
    __shared__ alignas(64) _Float16 hs[64];
    __shared__ float Ax[192];
    const f16x16* hsv = (const f16x16*)hs;
    float h = 0.f;
    if (g < 64) hs[g] = (_Float16)0.f;
    __syncthreads();
    float p0 = 0.f, p1 = 0.f, p2 = 0.f;  // gi prefetch (lanes<64 only)
    if (g < 64) { p0 = gi[g]; p1 = gi[64 + g]; p2 = gi[128 + g]; }
#define LGKM_BARRIER() do { \
    asm volatile("s_waitcnt lgkmcnt(0)" ::: "memory"); \
    __builtin_amdgcn_s_barrier(); \
    asm volatile("" ::: "memory"); \
} while (0)
#define DOT8(W, H, ACC) _Pragma("unroll") \
    for (int i_ = 0; i_ < 8; i_++) { \
        half2_t wa_; wa_[0] = (W)[2*i_]; wa_[1] = (W)[2*i_+1]; \
        half2_t ha_; ha_[0] = (H)[2*i_]; ha_[1] = (H)[2*i_+1]; \
        ACC = __builtin_amdgcn_fdot2(wa_, ha_, ACC, false); \
    }
#pragma unroll 1
    for (int m = 0; m < HP; m++) {
        f16x16 hv0 = hsv[0], hv1 = hsv[1], hv2 = hsv[2], hv3 = hsv[3];
        float c0 = p0, c1 = p1, c2 = p2;
        if (g < 64 && m + 1 < HP) {
            const float* gp = gi + (size_t)(m + 1) * 192;
            p0 = gp[g]; p1 = gp[64 + g]; p2 = gp[128 + g];
        }
        float a0 = 0.f, a1 = 0.f, a2 = 0.f, a3 = 0.f;
        DOT8(w0, hv0, a0)
        DOT8(w1, hv1, a1)
        DOT8(w2, hv2, a2)
        DOT8(w3, hv3, a3)
        float a = (a0 + a1) + (a2 + a3) + bh;
        Ax[g] = a;
        LGKM_BARRIER();                       // Ax visible; no vmcnt drain
        if (g < 64) {
            float az = Ax[64 + g], an = Ax[128 + g];
            float rg = 1.f / (1.f + __expf(-(c0 + a)));
            float zg = 1.f / (1.f + __expf(-(c1 + az)));
            float pre = c2 + rg * an;
            float ex = __expf(2.f * pre);
            float nn = 1.f - 2.f / (ex + 1.f);      // tanh, overflow-safe
            h = (1.f - zg) * nn + zg * h;
            hs[g] = (_Float16)h;
            out[(size_t)m * 64 + g] = h;            // store stays in flight
        }
        LGKM_BARRIER();                       // h visible; no vmcnt drain
    }
#undef DOT8
#undef LGKM_BARRIER
}

// ---------------- alignment column stats (online softmax over m) ----------
__global__ __launch_bounds__(256) void astat_k(const float* __restrict__ e,
        const float* __restrict__ t, float* __restrict__ pM,
        float* __restrict__ pZ) {
    __shared__ alignas(16) float Ts[64][68];
    __shared__ float Ms[4][64], Zs[4][64];
    int tid = threadIdx.x;
    int nl = tid & 63, ms = tid >> 6;
    int n0 = blockIdx.x * 64;
#pragma unroll
    for (int i = 0; i < 16; i++) {
        int idx = tid + i * 256;
        int rr = idx >> 6, kk = idx & 63;
        int n = n0 + rr;
        Ts[rr][kk] = (n < HP) ? t[(size_t)n * 64 + kk] : 0.f;
    }
    __syncthreads();
    float M = -1e30f, Z = 0.f;
    int m0 = blockIdx.y * 510;
    const float4* Trow = (const float4*)&Ts[nl][0];
    for (int m = m0 + ms; m < m0 + 510; m += 4) {
        const float4* er = (const float4*)(e + (size_t)m * 64);
        float a0 = 0, a1 = 0, a2 = 0, a3 = 0;
#pragma unroll
        for (int i = 0; i < 16; i++) {
            float4 evv = er[i], tv = Trow[i];
            a0 = fmaf(evv.x, tv.x, a0); a1 = fmaf(evv.y, tv.y, a1);
            a2 = fmaf(evv.z, tv.z, a2); a3 = fmaf(evv.w, tv.w, a3);
        }
        float s = (a0 + a1) + (a2 + a3);
        float nM = fmaxf(M, s);
        Z = Z * __expf(M - nM) + __expf(s - nM);
        M = nM;
    }
    Ms[ms][nl] = M; Zs[ms][nl] = Z;
    __syncthreads();
    if (ms == 0) {
#pragma unroll
        for (int i = 1; i < 4; i++) {
            float m2 = Ms[i][nl], z2 = Zs[i][nl];
            float nM = fmaxf(M, m2);
            Z = Z * __expf(M - nM) + z2 * __expf(m2 - nM);
            M = nM;
        }
        int n = n0 + nl;
        if (n < HP) { pM[(size_t)blockIdx.y * HP + n] = M; pZ[(size_t)blockIdx.y * HP + n] = Z; }
    }
}

// ---------------- attention logits ----------------
__global__ __launch_bounds__(256) void attnlog_k(const float* __restrict__ e,
        const float* __restrict__ aw, const float* __restrict__ ab,
        float* __restrict__ alog) {
    int m = blockIdx.x * 256 + threadIdx.x;
    if (m >= HP) return;
    float acc = ab[0];
    const float4* er = (const float4*)(e + (size_t)m * 64);
    const float4* ar = (const float4*)aw;
#pragma unroll
    for (int i = 0; i < 16; i++) {
        float4 evv = er[i], av = ar[i];
        acc += evv.x * av.x + evv.y * av.y + evv.z * av.z + evv.w * av.w;
    }
    alog[m] = acc;
}

// ---------------- reduce partial stats + attn softmax stats ---------------
__global__ __launch_bounds__(256) void reduce_k(const float* __restrict__ pM,
        const float* __restrict__ pZ, float* __restrict__ Mn,
        float* __restrict__ Zn, const float* __restrict__ alog,
        float* __restrict__ scal) {
    int tid = threadIdx.x;
    if (blockIdx.x < 16) {
        int n = blockIdx.x * 256 + tid;
        if (n >= HP) return;
        float M = pM[n], Z = pZ[n];
#pragma unroll
        for (int y = 1; y < 8; y++) {
            float m2 = pM[(size_t)y * HP + n], z2 = pZ[(size_t)y * HP + n];
            float nM = fmaxf(M, m2);
            Z = Z * __expf(M - nM) + z2 * __expf(m2 - nM);
            M = nM;
        }
        Mn[n] = M; Zn[n] = Z;
    } else {
        __shared__ float red[256];
        float m = -1e30f;
        for (int i = tid; i < HP; i += 256) m = fmaxf(m, alog[i]);
        red[tid] = m; __syncthreads();
        for (int s = 128; s > 0; s >>= 1) {
            if (tid < s) red[tid] = fmaxf(red[tid], red[tid + s]);
            __syncthreads();
        }
        float Ma = red[0]; __syncthreads();
        float z = 0.f;
        for (int i = tid; i < HP; i += 256) z += __expf(alog[i] - Ma);
        red[tid] = z; __syncthreads();
        for (int s = 128; s > 0; s >>= 1) {
            if (tid < s) red[tid] += red[tid + s];
            __syncthreads();
        }
        if (tid == 0) { scal[0] = Ma; scal[1] = red[0]; }
    }
}

// ---------------- Wmat rows m<64 ----------------
__global__ __launch_bounds__(256) void wmat_k(const float* __restrict__ e,
        const float* __restrict__ t, const float* __restrict__ Mn,
        const float* __restrict__ Zn, float* __restrict__ Wm) {
    __shared__ alignas(16) float Es[64][68];
    int tid = threadIdx.x;
#pragma unroll
    for (int i = 0; i < 16; i++) {
        int idx = tid + i * 256;
        int rr = idx >> 6, kk = idx & 63;
        Es[rr][kk] = e[(size_t)rr * 64 + kk];
    }
    __syncthreads();
    int n = blockIdx.x * 256 + tid;
    if (n >= HP) return;
    float tn[64];
    const float4* tr = (const float4*)(t + (size_t)n * 64);
    float4* tn4 = (float4*)tn;
#pragma unroll
    for (int i = 0; i < 16; i++) tn4[i] = tr[i];
    float mM = Mn[n], iZ = 1.f / Zn[n];
#pragma unroll 1
    for (int m = 0; m < 64; m++) {
        const float4* Er = (const float4*)&Es[m][0];
        float a0 = 0, a1 = 0, a2 = 0, a3 = 0;
#pragma unroll
        for (int i = 0; i < 16; i++) {
            float4 evv = Er[i], tv = tn4[i];
            a0 = fmaf(evv.x, tv.x, a0); a1 = fmaf(evv.y, tv.y, a1);
            a2 = fmaf(evv.z, tv.z, a2); a3 = fmaf(evv.w, tv.w, a3);
        }
        float s = (a0 + a1) + (a2 + a3);
        Wm[(size_t)m * HP + n] = __expf(s - mM) * iZ;
    }
}

// ---------------- t_prim = Wm(64 x 4080) @ t(4080 x 64), K-split atomics ---
__global__ __launch_bounds__(256) void tprim_k(const float* __restrict__ Wm,
        const float* __restrict__ t, float* __restrict__ tp) {
    __shared__ float Ws[64][64];
    __shared__ float Ts[64][64];
    int tid = threadIdx.x;
    int n0 = blockIdx.x * 64;
#pragma unroll
    for (int i = 0; i < 16; i++) {
        int idx = tid + i * 256;
        int r = idx >> 6, c = idx & 63;
        Ws[r][c] = (n0 + c < HP) ? Wm[(size_t)r * HP + n0 + c] : 0.f;
        Ts[r][c] = (n0 + r < HP) ? t[(size_t)(n0 + r) * 64 + c] : 0.f;
    }
    __syncthreads();
    int d = tid & 63, mg = tid >> 6;
    float acc[16];
#pragma unroll
    for (int i = 0; i < 16; i++) acc[i] = 0.f;
    for (int k = 0; k < 64; k++) {
        float tv = Ts[k][d];
#pragma unroll
        for (int mm = 0; mm < 16; mm++) acc[mm] = fmaf(Ws[mg * 16 + mm][k], tv, acc[mm]);
    }
#pragma unroll
    for (int mm = 0; mm < 16; mm++)
        atomicAdd(&tp[(size_t)(mg * 16 + mm) * 64 + d], acc[mm]);
}

// ---------------- epilogue ----------------
__global__ __launch_bounds__(256) void final_k(const float* __restrict__ tp,
        const float* __restrict__ e, const float* __restrict__ alog,
        const float* __restrict__ scal, const float* __restrict__ l3w,
        const float* __restrict__ l3b, const float* __restrict__ cw,
        const float* __restrict__ cb, float* __restrict__ out) {
    __shared__ float r1[64], hid[128];
    int tid = threadIdx.x;
    float Ma = scal[0], iZa = 1.f / scal[1];
    if (tid < 64) {
        float acc = 0.f;
        for (int m = 0; m < 64; m++) {
            float a = __expf(alog[m] - Ma) * iZa;
            acc += fabsf(tp[m * 64 + tid] - e[m * 64 + tid]) * a;
        }
        r1[tid] = fmaxf(acc, 0.f);
    }
    __syncthreads();
    if (tid < 128) {
        float acc = l3b[tid];
        for (int d = 0; d < 64; d++) acc = fmaf(r1[d], l3w[tid * 64 + d], acc);
        hid[tid] = fmaxf(acc, 0.f);
    }
    __syncthreads();
    if (tid < 2) {
        float acc = cb[tid];
        for (int j = 0; j < 128; j++) acc = fmaf(hid[j], cw[tid * 128 + j], acc);
        out[tid] = acc;
    }
}

// ---------------- weight packing ----------------
// l1w half2 K-pair pack: Wt2[(kk*64+j)*2 + {0,1}] = (w[j][2kk], w[j][2kk+1])
__global__ __launch_bounds__(256) void pack_l1w2_k(const float* __restrict__ w,
        _Float16* __restrict__ wt2) {
    int idx = blockIdx.x * 256 + threadIdx.x;
    if (idx >= (KF / 2) * 64) return;
    int kk = idx >> 6, j = idx & 63;
    wt2[(size_t)idx * 2 + 0] = (_Float16)w[(size_t)j * KF + 2 * kk];
    wt2[(size_t)idx * 2 + 1] = (_Float16)w[(size_t)j * KF + 2 * kk + 1];
}
__global__ __launch_bounds__(256) void pack_w1_k(const float* __restrict__ w,
        float* __restrict__ wp) {
    int idx = blockIdx.x * 256 + threadIdx.x;
    if (idx >= 400) return;
    int k = idx >> 4, co = idx & 15;
    wp[idx] = w[co * 25 + k];
}
// conv2 dot2 pack: entry (ci,q,co) -> half2 (taps 2q, 2q+1; pad 0)
__global__ __launch_bounds__(256) void pack_w2p_k(const float* __restrict__ w,
        _Float16* __restrict__ wp2) {
    int idx = blockIdx.x * 256 + threadIdx.x;
    if (idx >= 16 * 13 * 32) return;
    int co = idx & 31; int rest = idx >> 5;
    int q = rest % 13, ci = rest / 13;
    int t0 = 2 * q, t1 = 2 * q + 1;
    float v0 = (t0 < 25) ? w[co * 400 + ci * 25 + t0] : 0.f;
    float v1 = (t1 < 25) ? w[co * 400 + ci * 25 + t1] : 0.f;
    wp2[(size_t)idx * 2 + 0] = (_Float16)v0;
    wp2[(size_t)idx * 2 + 1] = (_Float16)v1;
}
// conv3 dot2 pack: entry (ci,q,co), co<64
__global__ __launch_bounds__(256) void pack_w3p_k(const float* __restrict__ w,
        _Float16* __restrict__ wp2) {
    int idx = blockIdx.x * 256 + threadIdx.x;
    if (idx >= 32 * 13 * 64) return;
    int co = idx & 63; int rest = idx >> 6;
    int q = rest % 13, ci = rest / 13;
    int t0 = 2 * q, t1 = 2 * q + 1;
    float v0 = (t0 < 25) ? w[co * 800 + ci * 25 + t0] : 0.f;
    float v1 = (t1 < 25) ? w[co * 800 + ci * 25 + t1] : 0.f;
    wp2[(size_t)idx * 2 + 0] = (_Float16)v0;
    wp2[(size_t)idx * 2 + 1] = (_Float16)v1;
}
__global__ __launch_bounds__(256) void pack_wih_k(const float* __restrict__ wih,
        const float* __restrict__ bih, const float* __restrict__ l1b,
        const float* __restrict__ whh, float* __restrict__ wiht,
        float* __restrict__ bc, _Float16* __restrict__ whh_h) {
    int idx = blockIdx.x * 256 + threadIdx.x;
    if (idx < 12288) {
        int g = idx % 192, k = idx / 192;
        wiht[idx] = wih[g * 64 + k];
        whh_h[idx] = (_Float16)whh[idx];
    }
    if (idx < 192) {
        float acc = bih[idx];
#pragma unroll
        for (int k = 0; k < 64; k++) acc = fmaf(wih[idx * 64 + k], l1b[k], acc);
        bc[idx] = acc;
    }
}

// ---------------- host ----------------
extern "C" void kernel_launch(void* const* d_in, const int* in_sizes, int n_in,
                              void* d_out, int out_size, void* d_ws, size_t ws_size,
                              hipStream_t stream) {
    const float* ev    = (const float*)d_in[0];
    const float* tmpl  = (const float*)d_in[1];
    const float* w1    = (const float*)d_in[2];
    const float* b1    = (const float*)d_in[3];
    const float* w2    = (const float*)d_in[4];
    const float* b2    = (const float*)d_in[5];
    const float* w3    = (const float*)d_in[6];
    const float* b3    = (const float*)d_in[7];
    const float* l1w   = (const float*)d_in[8];
    const float* l1b   = (const float*)d_in[9];
    const float* wih   = (const float*)d_in[10];
    const float* whh   = (const float*)d_in[11];
    const float* bih   = (const float*)d_in[12];
    const float* bhh   = (const float*)d_in[13];
    const float* aw    = (const float*)d_in[14];
    const float* ab    = (const float*)d_in[15];
    const float* l3w   = (const float*)d_in[16];
    const float* l3b   = (const float*)d_in[17];
    const float* cw    = (const float*)d_in[18];
    const float* cb    = (const float*)d_in[19];
    float* out = (float*)d_out;
    (void)in_sizes; (void)n_in; (void)out_size;

    char* ws = (char*)d_ws;
    size_t off = 0;
    auto alloc = [&](size_t bytes) -> char* {
        char* p = ws + off;
        off += (bytes + 255) & ~(size_t)255;
        return p;
    };
    size_t szA = (size_t)C3 * H3 * W3 * 2;                 // fp16 conv3 out (> conv1 out fp16)
    char*  A    = alloc(szA);
    char*  B    = alloc((size_t)C2 * H2 * W2 * 2);         // conv2 fp16 out
    _Float16* P16 = (_Float16*)alloc((size_t)HP * KF * 2); // pooled fp16
    _Float16* Wt2 = (_Float16*)alloc((size_t)KF * 64 * 2); // lin1 fp16 pairs
    float* w1p  = (float*)alloc(400 * 4);
    _Float16* w2p2 = (_Float16*)alloc(16 * 13 * 32 * 2 * 2);
    _Float16* w3p2 = (_Float16*)alloc(32 * 13 * 64 * 2 * 2);
    float* wiht = (float*)alloc(12288 * 4);
    _Float16* whhh = (_Float16*)alloc(12288 * 2);
    float* bc   = (float*)alloc(256 * 4);
    float* L    = (float*)alloc((size_t)HP * 64 * 4);
    float* gi0  = (float*)alloc((size_t)HP * 192 * 4);
    float* gi1  = (float*)alloc((size_t)HP * 192 * 4);
    float* ebuf = (float*)alloc((size_t)HP * 64 * 4);
    float* tbuf = (float*)alloc((size_t)HP * 64 * 4);
    float* pM   = (float*)alloc((size_t)8 * HP * 4);
    float* pZ   = (float*)alloc((size_t)8 * HP * 4);
    float* Mn   = (float*)alloc(HP * 4);
    float* Zn   = (float*)alloc(HP * 4);
    float* Wm   = (float*)alloc((size_t)64 * HP * 4);
    float* alog = (float*)alloc(HP * 4);
    float* tpm  = (float*)alloc(64 * 64 * 4);
    float* scal = (float*)alloc(256);
    if (off > ws_size) return;   // workspace too small: bail loudly (validation fails)

    pack_l1w2_k<<<dim3(((KF / 2) * 64 + 255) / 256), dim3(256), 0, stream>>>(l1w, Wt2);
    pack_w1_k<<<dim3(2), dim3(256), 0, stream>>>(w1, w1p);
    pack_w2p_k<<<dim3((16 * 13 * 32 + 255) / 256), dim3(256), 0, stream>>>(w2, w2p2);
    pack_w3p_k<<<dim3((32 * 13 * 64 + 255) / 256), dim3(256), 0, stream>>>(w3, w3p2);
    pack_wih_k<<<dim3(48), dim3(256), 0, stream>>>(wih, bih, l1b, whh, wiht, bc, whhh);

    for (int bsel = 0; bsel < 2; bsel++) {
        const float* xin = bsel ? tmpl : ev;
        float* gib = bsel ? gi1 : gi0;
        conv1_k<<<dim3((H1 * W1 + 255) / 256), dim3(256), 0, stream>>>(xin, w1p, b1, (__half*)A);
        conv2_k<<<dim3(2, (H2 * W2 + 255) / 256), dim3(256), 0, stream>>>((const __half*)A, w2p2, b2, (__half*)B);
        conv3_k<<<dim3(4, (H3 * W3 + 255) / 256), dim3(256), 0, stream>>>((const __half*)B, w3p2, b3, (__half*)A);
        pool_k<<<dim3((C3 * HP * WPW + 255) / 256), dim3(256), 0, stream>>>((const __half*)A, P16);
        hipMemsetAsync(L, 0, (size_t)HP * 64 * 4, stream);
        lin1_k<<<dim3(64, 4), dim3(256), 0, stream>>>(P16, Wt2, L);
        gi_k<<<dim3(HP / 8), dim3(192), 0, stream>>>(L, wiht, bc, gib);
    }
    gru_k<<<dim3(2), dim3(192), 0, stream>>>(gi0, gi1, whhh, bhh, ebuf, tbuf);
    astat_k<<<dim3(64, 8), dim3(256), 0, stream>>>(ebuf, tbuf, pM, pZ);
    attnlog_k<<<dim3(16), dim3(256), 0, stream>>>(ebuf, aw, ab, alog);
    reduce_k<<<dim3(17), dim3(256), 0, stream>>>(pM, pZ, Mn, Zn, alog, scal);
    wmat_k<<<dim3(16), dim3(256), 0, stream>>>(ebuf, tbuf, Mn, Zn, Wm);
    hipMemsetAsync(tpm, 0, 64 * 64 * 4, stream);
    tprim_k<<<dim3(64), dim3(256), 0, stream>>>(Wm, tbuf, tpm);
    final_k<<<dim3(1), dim3(256), 0, stream>>>(tpm, ebuf, alog, scal, l3w, l3b, cw, cb, out);
}